// Round 2
// baseline (2636.401 us; speedup 1.0000x reference)
//
#include <hip/hip_runtime.h>
#include <math.h>

#define HW    4096      // 64*64
#define NCH   256       // C
#define NB    4         // batch

// ws layout (floats), total 3,178,496 fl = 12.71 MB:
//   rr[n][64][4096]   : 1,048,576  (r1 rows 0-31, r2 rows 32-63)
//   mbuf[n][4096]     : 16,384
//   lbuf[n][4096]     : 16,384
//   vt[n][4096][128]  : 2,097,152  (v transposed, one 128-wide C-chunk at a time)

// ---------------------------------------------------------------------------
// rr[n][r][i] = sum_c W[r][c] * x[n][c][i], W = [w1;w2]  (64 rows)
// grid (64 i-blocks, 4 n), 256 threads, tile 64x64, K-step 16
// ---------------------------------------------------------------------------
__global__ __launch_bounds__(256) void proj_rr_kernel(
    const float* __restrict__ x, const float* __restrict__ w1,
    const float* __restrict__ w2, float* __restrict__ rr)
{
    __shared__ float aT[16][68];   // [k][m]
    __shared__ float bS[16][68];   // [k][i]

    const int t  = threadIdx.x;
    const int i0 = blockIdx.x * 64;
    const int n  = blockIdx.y;

    const int tm = t >> 4;
    const int ti = t & 15;

    const int ar = t >> 2;          // 0..63
    const int ak = (t & 3) * 4;
    const float* arow = (ar < 32) ? (w1 + (size_t)ar * NCH)
                                  : (w2 + (size_t)(ar - 32) * NCH);
    const float* xb = x + (size_t)n * NCH * HW;

    float acc[4][4] = {};

    for (int kc = 0; kc < NCH; kc += 16) {
        float4 av = *reinterpret_cast<const float4*>(arow + kc + ak);
        float4 bv = *reinterpret_cast<const float4*>(
            xb + (size_t)(kc + (t >> 4)) * HW + i0 + (t & 15) * 4);
        __syncthreads();
        aT[ak + 0][ar] = av.x;
        aT[ak + 1][ar] = av.y;
        aT[ak + 2][ar] = av.z;
        aT[ak + 3][ar] = av.w;
        *reinterpret_cast<float4*>(&bS[t >> 4][(t & 15) * 4]) = bv;
        __syncthreads();
        #pragma unroll
        for (int kk = 0; kk < 16; ++kk) {
            float4 a4 = *reinterpret_cast<const float4*>(&aT[kk][tm * 4]);
            float4 b4 = *reinterpret_cast<const float4*>(&bS[kk][ti * 4]);
            float a[4] = {a4.x, a4.y, a4.z, a4.w};
            float b[4] = {b4.x, b4.y, b4.z, b4.w};
            #pragma unroll
            for (int mm = 0; mm < 4; ++mm)
                #pragma unroll
                for (int jj = 0; jj < 4; ++jj)
                    acc[mm][jj] = fmaf(a[mm], b[jj], acc[mm][jj]);
        }
    }

    float* op = rr + (size_t)n * 64 * HW;
    #pragma unroll
    for (int mm = 0; mm < 4; ++mm) {
        float4 r;
        r.x = acc[mm][0]; r.y = acc[mm][1]; r.z = acc[mm][2]; r.w = acc[mm][3];
        *reinterpret_cast<float4*>(op + (size_t)(tm * 4 + mm) * HW + i0 + ti * 4) = r;
    }
}

// ---------------------------------------------------------------------------
// vt[n][i][cl] = sum_k x[n][k][i] * wv[c0+cB+cl][k]   (v transposed)
// grid (64 i-blocks, 2 c-blocks, 4 n), 256 threads, tile 64i x 64c
// ---------------------------------------------------------------------------
__global__ __launch_bounds__(256) void proj_vt_kernel(
    const float* __restrict__ x, const float* __restrict__ wv,
    float* __restrict__ vt, int c0)
{
    __shared__ float xs[16][68];    // [k][i]
    __shared__ float wsT[16][68];   // [k][c]

    const int t  = threadIdx.x;
    const int i0 = blockIdx.x * 64;
    const int cB = blockIdx.y * 64;
    const int n  = blockIdx.z;

    const int im = t >> 4;    // i-quad
    const int jc = t & 15;    // c-quad

    const int cr = t >> 2;          // 0..63
    const int ck = (t & 3) * 4;
    const float* wrow = wv + (size_t)(c0 + cB + cr) * NCH;
    const float* xb = x + (size_t)n * NCH * HW;

    float acc[4][4] = {};

    for (int kc = 0; kc < NCH; kc += 16) {
        float4 xv = *reinterpret_cast<const float4*>(
            xb + (size_t)(kc + (t >> 4)) * HW + i0 + (t & 15) * 4);
        float4 wvv = *reinterpret_cast<const float4*>(wrow + kc + ck);
        __syncthreads();
        *reinterpret_cast<float4*>(&xs[t >> 4][(t & 15) * 4]) = xv;
        wsT[ck + 0][cr] = wvv.x;
        wsT[ck + 1][cr] = wvv.y;
        wsT[ck + 2][cr] = wvv.z;
        wsT[ck + 3][cr] = wvv.w;
        __syncthreads();
        #pragma unroll
        for (int kk = 0; kk < 16; ++kk) {
            float4 a4 = *reinterpret_cast<const float4*>(&xs[kk][im * 4]);
            float4 b4 = *reinterpret_cast<const float4*>(&wsT[kk][jc * 4]);
            float a[4] = {a4.x, a4.y, a4.z, a4.w};
            float b[4] = {b4.x, b4.y, b4.z, b4.w};
            #pragma unroll
            for (int ii = 0; ii < 4; ++ii)
                #pragma unroll
                for (int cc = 0; cc < 4; ++cc)
                    acc[ii][cc] = fmaf(a[ii], b[cc], acc[ii][cc]);
        }
    }

    float* op = vt + (size_t)n * HW * 128;
    #pragma unroll
    for (int ii = 0; ii < 4; ++ii) {
        float4 r;
        r.x = acc[ii][0]; r.y = acc[ii][1]; r.z = acc[ii][2]; r.w = acc[ii][3];
        *reinterpret_cast<float4*>(
            op + (size_t)(i0 + im * 4 + ii) * 128 + cB + jc * 4) = r;
    }
}

// ---------------------------------------------------------------------------
// Row softmax stats: m_i = max_j S[i][j], l_i = sum_j exp(S[i][j]-m_i)
// S[i][j] = sum_o r1[o][i]*r2[o][j].  grid (64 i-blocks, 4 n), 512 threads.
// ---------------------------------------------------------------------------
__global__ __launch_bounds__(512) void stats_kernel(
    const float* __restrict__ rr, float* __restrict__ mbuf,
    float* __restrict__ lbuf)
{
    __shared__ float r1t[32][64];
    __shared__ float r2t[32][128];

    const int t  = threadIdx.x;
    const int i0 = blockIdx.x * 64;
    const int n  = blockIdx.y;

    const float* r1 = rr + (size_t)n * 64 * HW;
    const float* r2 = r1 + (size_t)32 * HW;

    {
        int o = t >> 4, c4 = (t & 15) * 4;
        *reinterpret_cast<float4*>(&r1t[o][c4]) =
            *reinterpret_cast<const float4*>(r1 + (size_t)o * HW + i0 + c4);
    }

    const int ti = t >> 5;   // 0..15
    const int tj = t & 31;   // 0..31
    float m[4], l[4];
    #pragma unroll
    for (int ii = 0; ii < 4; ++ii) { m[ii] = -INFINITY; l[ii] = 0.f; }

    for (int jb = 0; jb < 32; ++jb) {
        const int j0 = jb * 128;
        __syncthreads();
        {
            int o = t >> 4, c4 = (t & 15) * 4;
            *reinterpret_cast<float4*>(&r2t[o][c4]) =
                *reinterpret_cast<const float4*>(r2 + (size_t)o * HW + j0 + c4);
            *reinterpret_cast<float4*>(&r2t[o][c4 + 64]) =
                *reinterpret_cast<const float4*>(r2 + (size_t)o * HW + j0 + c4 + 64);
        }
        __syncthreads();

        float s[4][4] = {};
        #pragma unroll 8
        for (int o = 0; o < 32; ++o) {
            float4 a4 = *reinterpret_cast<const float4*>(&r1t[o][ti * 4]);
            float4 b4 = *reinterpret_cast<const float4*>(&r2t[o][tj * 4]);
            float a[4] = {a4.x, a4.y, a4.z, a4.w};
            float b[4] = {b4.x, b4.y, b4.z, b4.w};
            #pragma unroll
            for (int ii = 0; ii < 4; ++ii)
                #pragma unroll
                for (int jj = 0; jj < 4; ++jj)
                    s[ii][jj] = fmaf(a[ii], b[jj], s[ii][jj]);
        }

        #pragma unroll
        for (int ii = 0; ii < 4; ++ii) {
            float rm = fmaxf(fmaxf(s[ii][0], s[ii][1]), fmaxf(s[ii][2], s[ii][3]));
            for (int msk = 1; msk < 32; msk <<= 1)
                rm = fmaxf(rm, __shfl_xor(rm, msk, 64));
            float mn = fmaxf(m[ii], rm);
            float sum = __expf(s[ii][0] - mn) + __expf(s[ii][1] - mn)
                      + __expf(s[ii][2] - mn) + __expf(s[ii][3] - mn);
            for (int msk = 1; msk < 32; msk <<= 1)
                sum += __shfl_xor(sum, msk, 64);
            l[ii] = l[ii] * __expf(m[ii] - mn) + sum;
            m[ii] = mn;
        }
    }

    if (tj == 0) {
        #pragma unroll
        for (int ii = 0; ii < 4; ++ii) {
            mbuf[(size_t)n * HW + i0 + ti * 4 + ii] = m[ii];
            lbuf[(size_t)n * HW + i0 + ti * 4 + ii] = l[ii];
        }
    }
}

// ---------------------------------------------------------------------------
// attn chunk: out[n][c0+cl][j] = x + sc * sum_i vt[n][i][cl] * P[i][j]
// grid (64 j-blocks, 4 n), 256 threads, tile 64j x 128c, i-tile 64.
// V read straight from global (vt, broadcast-coalesced) — no LDS staging.
// ---------------------------------------------------------------------------
__global__ __launch_bounds__(256) void attn_kernel(
    const float* __restrict__ rr, const float* __restrict__ mbuf,
    const float* __restrict__ lbuf, const float* __restrict__ vt,
    const float* __restrict__ x, const float* __restrict__ scale,
    float* __restrict__ out, int c0)
{
    __shared__ float r2t[32][68];   // [o][j]  persistent
    __shared__ float r1t[32][68];   // [o][i]  per i-tile (64 wide)
    __shared__ float Pt[64][68];    // [i][j]
    __shared__ float ms[64], ils[64];

    const int t  = threadIdx.x;
    const int j0 = blockIdx.x * 64;
    const int n  = blockIdx.y;

    const float* r1  = rr + (size_t)n * 64 * HW;
    const float* r2  = r1 + (size_t)32 * HW;
    const float* vtb = vt + (size_t)n * HW * 128;

    {   // persistent r2 tile 32x64: 8 floats/thread
        int o = t >> 3, c4 = (t & 7) * 4;
        *reinterpret_cast<float4*>(&r2t[o][c4]) =
            *reinterpret_cast<const float4*>(r2 + (size_t)o * HW + j0 + c4);
        *reinterpret_cast<float4*>(&r2t[o][c4 + 32]) =
            *reinterpret_cast<const float4*>(r2 + (size_t)o * HW + j0 + c4 + 32);
    }

    const int tj = t & 15;    // j-quad
    const int tc = t >> 4;    // 0..15 : c = tc*8 + q
    const int iq = t >> 4;    // S phase: i = iq*4 + di

    float acc[4][8] = {};     // [jj][q]

    for (int it = 0; it < 64; ++it) {
        const int i0 = it * 64;
        __syncthreads();   // prev PV done; r2t visible on first pass

        {   // stage r1 tile 32x64
            int o = t >> 3, c4 = (t & 7) * 4;
            *reinterpret_cast<float4*>(&r1t[o][c4]) =
                *reinterpret_cast<const float4*>(r1 + (size_t)o * HW + i0 + c4);
            *reinterpret_cast<float4*>(&r1t[o][c4 + 32]) =
                *reinterpret_cast<const float4*>(r1 + (size_t)o * HW + i0 + c4 + 32);
        }
        if (t < 64) {
            ms[t]  = mbuf[(size_t)n * HW + i0 + t];
            ils[t] = 1.0f / lbuf[(size_t)n * HW + i0 + t];
        }
        __syncthreads();

        // S phase: thread computes S[iq*4+di][tj*4+jj], di,jj in 0..3
        float s[4][4] = {};
        #pragma unroll 8
        for (int o = 0; o < 32; ++o) {
            float4 a4 = *reinterpret_cast<const float4*>(&r1t[o][iq * 4]);
            float4 b4 = *reinterpret_cast<const float4*>(&r2t[o][tj * 4]);
            float a[4] = {a4.x, a4.y, a4.z, a4.w};
            float b[4] = {b4.x, b4.y, b4.z, b4.w};
            #pragma unroll
            for (int di = 0; di < 4; ++di)
                #pragma unroll
                for (int jj = 0; jj < 4; ++jj)
                    s[di][jj] = fmaf(a[di], b[jj], s[di][jj]);
        }
        #pragma unroll
        for (int di = 0; di < 4; ++di) {
            int i = iq * 4 + di;
            float mi = ms[i], li = ils[i];
            float4 p;
            p.x = __expf(s[di][0] - mi) * li;
            p.y = __expf(s[di][1] - mi) * li;
            p.z = __expf(s[di][2] - mi) * li;
            p.w = __expf(s[di][3] - mi) * li;
            *reinterpret_cast<float4*>(&Pt[i][tj * 4]) = p;
        }
        __syncthreads();

        // PV: acc[jj][q] += P[ii][j] * v[ii][c]; V from global (L2 broadcast)
        #pragma unroll 8
        for (int ii = 0; ii < 64; ++ii) {
            float4 p4 = *reinterpret_cast<const float4*>(&Pt[ii][tj * 4]);
            const float* vrow = vtb + (size_t)(i0 + ii) * 128 + tc * 8;
            float4 va = *reinterpret_cast<const float4*>(vrow);
            float4 vb = *reinterpret_cast<const float4*>(vrow + 4);
            float p[4]  = {p4.x, p4.y, p4.z, p4.w};
            float vv[8] = {va.x, va.y, va.z, va.w, vb.x, vb.y, vb.z, vb.w};
            #pragma unroll
            for (int jj = 0; jj < 4; ++jj)
                #pragma unroll
                for (int q = 0; q < 8; ++q)
                    acc[jj][q] = fmaf(p[jj], vv[q], acc[jj][q]);
        }
    }

    // epilogue: out = x + sc * attn, rows c0+tc*8+q, cols j0+tj*4
    const float sc = scale[0];
    const float* xb = x   + (size_t)n * NCH * HW;
    float*       ob = out + (size_t)n * NCH * HW;
    #pragma unroll
    for (int q = 0; q < 8; ++q) {
        size_t off = (size_t)(c0 + tc * 8 + q) * HW + j0 + tj * 4;
        float4 xv = *reinterpret_cast<const float4*>(xb + off);
        float4 r;
        r.x = xv.x + sc * acc[0][q];
        r.y = xv.y + sc * acc[1][q];
        r.z = xv.z + sc * acc[2][q];
        r.w = xv.w + sc * acc[3][q];
        *reinterpret_cast<float4*>(ob + off) = r;
    }
}

extern "C" void kernel_launch(void* const* d_in, const int* in_sizes, int n_in,
                              void* d_out, int out_size, void* d_ws, size_t ws_size,
                              hipStream_t stream) {
    (void)in_sizes; (void)n_in; (void)out_size; (void)ws_size;
    const float* x  = (const float*)d_in[0];
    const float* w1 = (const float*)d_in[1];
    const float* w2 = (const float*)d_in[2];
    const float* wv = (const float*)d_in[3];
    const float* sc = (const float*)d_in[4];
    float* out = (float*)d_out;

    float* rr   = (float*)d_ws;                      // 1,048,576 fl
    float* mbuf = rr + (size_t)NB * 64 * HW;         // 16,384 fl
    float* lbuf = mbuf + (size_t)NB * HW;            // 16,384 fl
    float* vt   = lbuf + (size_t)NB * HW;            // 2,097,152 fl

    proj_rr_kernel<<<dim3(64, NB), 256, 0, stream>>>(x, w1, w2, rr);
    stats_kernel<<<dim3(64, NB), 512, 0, stream>>>(rr, mbuf, lbuf);
    for (int h = 0; h < 2; ++h) {
        proj_vt_kernel<<<dim3(64, 2, NB), 256, 0, stream>>>(x, wv, vt, h * 128);
        attn_kernel<<<dim3(64, NB), 256, 0, stream>>>(rr, mbuf, lbuf, vt, x, sc,
                                                      out, h * 128);
    }
}

// Round 3
// 1317.942 us; speedup vs baseline: 2.0004x; 2.0004x over previous
//
#include <hip/hip_runtime.h>
#include <math.h>

#define HW    4096      // 64*64
#define NCH   256       // C
#define NB    4         // batch

// ws layout (floats), total 3,178,496 fl = 12.71 MB:
//   rr[n][64][4096]   : 1,048,576  (r1 rows 0-31, r2 rows 32-63)
//   mbuf[n][4096]     : 16,384
//   lbuf[n][4096]     : 16,384
//   vt[n][4096][128]  : 2,097,152  (v transposed, one 128-wide C-chunk at a time)

// ---------------------------------------------------------------------------
// rr[n][r][i] = sum_c W[r][c] * x[n][c][i], W = [w1;w2]  (64 rows)
// ---------------------------------------------------------------------------
__global__ __launch_bounds__(256) void proj_rr_kernel(
    const float* __restrict__ x, const float* __restrict__ w1,
    const float* __restrict__ w2, float* __restrict__ rr)
{
    __shared__ float aT[16][68];   // [k][m]
    __shared__ float bS[16][68];   // [k][i]

    const int t  = threadIdx.x;
    const int i0 = blockIdx.x * 64;
    const int n  = blockIdx.y;

    const int tm = t >> 4;
    const int ti = t & 15;

    const int ar = t >> 2;          // 0..63
    const int ak = (t & 3) * 4;
    const float* arow = (ar < 32) ? (w1 + (size_t)ar * NCH)
                                  : (w2 + (size_t)(ar - 32) * NCH);
    const float* xb = x + (size_t)n * NCH * HW;

    float acc[4][4] = {};

    for (int kc = 0; kc < NCH; kc += 16) {
        float4 av = *reinterpret_cast<const float4*>(arow + kc + ak);
        float4 bv = *reinterpret_cast<const float4*>(
            xb + (size_t)(kc + (t >> 4)) * HW + i0 + (t & 15) * 4);
        __syncthreads();
        aT[ak + 0][ar] = av.x;
        aT[ak + 1][ar] = av.y;
        aT[ak + 2][ar] = av.z;
        aT[ak + 3][ar] = av.w;
        *reinterpret_cast<float4*>(&bS[t >> 4][(t & 15) * 4]) = bv;
        __syncthreads();
        #pragma unroll
        for (int kk = 0; kk < 16; ++kk) {
            float4 a4 = *reinterpret_cast<const float4*>(&aT[kk][tm * 4]);
            float4 b4 = *reinterpret_cast<const float4*>(&bS[kk][ti * 4]);
            float a[4] = {a4.x, a4.y, a4.z, a4.w};
            float b[4] = {b4.x, b4.y, b4.z, b4.w};
            #pragma unroll
            for (int mm = 0; mm < 4; ++mm)
                #pragma unroll
                for (int jj = 0; jj < 4; ++jj)
                    acc[mm][jj] = fmaf(a[mm], b[jj], acc[mm][jj]);
        }
    }

    float* op = rr + (size_t)n * 64 * HW;
    #pragma unroll
    for (int mm = 0; mm < 4; ++mm) {
        float4 r;
        r.x = acc[mm][0]; r.y = acc[mm][1]; r.z = acc[mm][2]; r.w = acc[mm][3];
        *reinterpret_cast<float4*>(op + (size_t)(tm * 4 + mm) * HW + i0 + ti * 4) = r;
    }
}

// ---------------------------------------------------------------------------
// vt[n][i][cl] = sum_k x[n][k][i] * wv[c0+cB+cl][k]   (v transposed)
// ---------------------------------------------------------------------------
__global__ __launch_bounds__(256) void proj_vt_kernel(
    const float* __restrict__ x, const float* __restrict__ wv,
    float* __restrict__ vt, int c0)
{
    __shared__ float xs[16][68];    // [k][i]
    __shared__ float wsT[16][68];   // [k][c]

    const int t  = threadIdx.x;
    const int i0 = blockIdx.x * 64;
    const int cB = blockIdx.y * 64;
    const int n  = blockIdx.z;

    const int im = t >> 4;    // i-quad
    const int jc = t & 15;    // c-quad

    const int cr = t >> 2;          // 0..63
    const int ck = (t & 3) * 4;
    const float* wrow = wv + (size_t)(c0 + cB + cr) * NCH;
    const float* xb = x + (size_t)n * NCH * HW;

    float acc[4][4] = {};

    for (int kc = 0; kc < NCH; kc += 16) {
        float4 xv = *reinterpret_cast<const float4*>(
            xb + (size_t)(kc + (t >> 4)) * HW + i0 + (t & 15) * 4);
        float4 wvv = *reinterpret_cast<const float4*>(wrow + kc + ck);
        __syncthreads();
        *reinterpret_cast<float4*>(&xs[t >> 4][(t & 15) * 4]) = xv;
        wsT[ck + 0][cr] = wvv.x;
        wsT[ck + 1][cr] = wvv.y;
        wsT[ck + 2][cr] = wvv.z;
        wsT[ck + 3][cr] = wvv.w;
        __syncthreads();
        #pragma unroll
        for (int kk = 0; kk < 16; ++kk) {
            float4 a4 = *reinterpret_cast<const float4*>(&xs[kk][im * 4]);
            float4 b4 = *reinterpret_cast<const float4*>(&wsT[kk][jc * 4]);
            float a[4] = {a4.x, a4.y, a4.z, a4.w};
            float b[4] = {b4.x, b4.y, b4.z, b4.w};
            #pragma unroll
            for (int ii = 0; ii < 4; ++ii)
                #pragma unroll
                for (int cc = 0; cc < 4; ++cc)
                    acc[ii][cc] = fmaf(a[ii], b[cc], acc[ii][cc]);
        }
    }

    float* op = vt + (size_t)n * HW * 128;
    #pragma unroll
    for (int ii = 0; ii < 4; ++ii) {
        float4 r;
        r.x = acc[ii][0]; r.y = acc[ii][1]; r.z = acc[ii][2]; r.w = acc[ii][3];
        *reinterpret_cast<float4*>(
            op + (size_t)(i0 + im * 4 + ii) * 128 + cB + jc * 4) = r;
    }
}

// ---------------------------------------------------------------------------
// Row softmax stats: m_i = max_j S[i][j], l_i = sum_j exp(S[i][j]-m_i)
// ---------------------------------------------------------------------------
__global__ __launch_bounds__(512) void stats_kernel(
    const float* __restrict__ rr, float* __restrict__ mbuf,
    float* __restrict__ lbuf)
{
    __shared__ float r1t[32][64];
    __shared__ float r2t[32][128];

    const int t  = threadIdx.x;
    const int i0 = blockIdx.x * 64;
    const int n  = blockIdx.y;

    const float* r1 = rr + (size_t)n * 64 * HW;
    const float* r2 = r1 + (size_t)32 * HW;

    {
        int o = t >> 4, c4 = (t & 15) * 4;
        *reinterpret_cast<float4*>(&r1t[o][c4]) =
            *reinterpret_cast<const float4*>(r1 + (size_t)o * HW + i0 + c4);
    }

    const int ti = t >> 5;   // 0..15
    const int tj = t & 31;   // 0..31
    float m[4], l[4];
    #pragma unroll
    for (int ii = 0; ii < 4; ++ii) { m[ii] = -INFINITY; l[ii] = 0.f; }

    for (int jb = 0; jb < 32; ++jb) {
        const int j0 = jb * 128;
        __syncthreads();
        {
            int o = t >> 4, c4 = (t & 15) * 4;
            *reinterpret_cast<float4*>(&r2t[o][c4]) =
                *reinterpret_cast<const float4*>(r2 + (size_t)o * HW + j0 + c4);
            *reinterpret_cast<float4*>(&r2t[o][c4 + 64]) =
                *reinterpret_cast<const float4*>(r2 + (size_t)o * HW + j0 + c4 + 64);
        }
        __syncthreads();

        float s[4][4] = {};
        #pragma unroll 8
        for (int o = 0; o < 32; ++o) {
            float4 a4 = *reinterpret_cast<const float4*>(&r1t[o][ti * 4]);
            float4 b4 = *reinterpret_cast<const float4*>(&r2t[o][tj * 4]);
            float a[4] = {a4.x, a4.y, a4.z, a4.w};
            float b[4] = {b4.x, b4.y, b4.z, b4.w};
            #pragma unroll
            for (int ii = 0; ii < 4; ++ii)
                #pragma unroll
                for (int jj = 0; jj < 4; ++jj)
                    s[ii][jj] = fmaf(a[ii], b[jj], s[ii][jj]);
        }

        #pragma unroll
        for (int ii = 0; ii < 4; ++ii) {
            float rm = fmaxf(fmaxf(s[ii][0], s[ii][1]), fmaxf(s[ii][2], s[ii][3]));
            for (int msk = 1; msk < 32; msk <<= 1)
                rm = fmaxf(rm, __shfl_xor(rm, msk, 64));
            float mn = fmaxf(m[ii], rm);
            float sum = __expf(s[ii][0] - mn) + __expf(s[ii][1] - mn)
                      + __expf(s[ii][2] - mn) + __expf(s[ii][3] - mn);
            for (int msk = 1; msk < 32; msk <<= 1)
                sum += __shfl_xor(sum, msk, 64);
            l[ii] = l[ii] * __expf(m[ii] - mn) + sum;
            m[ii] = mn;
        }
    }

    if (tj == 0) {
        #pragma unroll
        for (int ii = 0; ii < 4; ++ii) {
            mbuf[(size_t)n * HW + i0 + ti * 4 + ii] = m[ii];
            lbuf[(size_t)n * HW + i0 + ti * 4 + ii] = l[ii];
        }
    }
}

// ---------------------------------------------------------------------------
// attn: out[n][c0+cs*64+cl][j] = x + sc * sum_i vt[n][i][cs*64+cl] * P[i][j]
// grid (64 j-blocks, 2 c-splits, 4 n), 512 threads (= 512 blocks, 2/CU,
// 16 waves/CU = 50% occupancy). Tile 64 j x 64 c; i-tiles of 64.
// Per thread: 2j x 4c accumulators (8 outputs).
// ---------------------------------------------------------------------------
__global__ __launch_bounds__(512) void attn_kernel(
    const float* __restrict__ rr, const float* __restrict__ mbuf,
    const float* __restrict__ lbuf, const float* __restrict__ vt,
    const float* __restrict__ x, const float* __restrict__ scale,
    float* __restrict__ out, int c0)
{
    __shared__ float r2t[32][68];   // [o][j]  persistent
    __shared__ float r1t[32][68];   // [o][i]  per i-tile
    __shared__ float Pt[64][68];    // [i][j]
    __shared__ float ms[64], ils[64];

    const int t  = threadIdx.x;
    const int j0 = blockIdx.x * 64;
    const int cl0 = blockIdx.y * 64;   // c base within the 128-wide chunk
    const int n  = blockIdx.z;

    const float* r1  = rr + (size_t)n * 64 * HW;
    const float* r2  = r1 + (size_t)32 * HW;
    const float* vtb = vt + (size_t)n * HW * 128 + cl0;

    {   // persistent r2 tile 32x64: 1 float4/thread
        int o = t >> 4, c4 = (t & 15) * 4;
        *reinterpret_cast<float4*>(&r2t[o][c4]) =
            *reinterpret_cast<const float4*>(r2 + (size_t)o * HW + j0 + c4);
    }

    // S-phase mapping: i = iq*4+di (iq=t>>5, 0..15), j = jp*2+jj (jp=t&31)
    const int iq = t >> 5;
    const int jp = t & 31;
    // PV/epilogue mapping: j = tj2*2+jj (tj2=t&31), c = tc4*4+q (tc4=t>>5)
    const int tj2 = t & 31;
    const int tc4 = t >> 5;

    float acc[2][4] = {};   // [jj][q]

    for (int it = 0; it < 64; ++it) {
        const int i0 = it * 64;
        __syncthreads();   // prev PV done; r2t visible on first pass

        {   // stage r1 tile 32x64: 1 float4/thread
            int o = t >> 4, c4 = (t & 15) * 4;
            *reinterpret_cast<float4*>(&r1t[o][c4]) =
                *reinterpret_cast<const float4*>(r1 + (size_t)o * HW + i0 + c4);
        }
        if (t < 64) {
            ms[t]  = mbuf[(size_t)n * HW + i0 + t];
            ils[t] = 1.0f / lbuf[(size_t)n * HW + i0 + t];
        }
        __syncthreads();

        // S phase: s[di][jj] for i=iq*4+di, j=jp*2+jj
        float s[4][2] = {};
        #pragma unroll 8
        for (int o = 0; o < 32; ++o) {
            float4 a4 = *reinterpret_cast<const float4*>(&r1t[o][iq * 4]);
            float2 b2 = *reinterpret_cast<const float2*>(&r2t[o][jp * 2]);
            float a[4] = {a4.x, a4.y, a4.z, a4.w};
            #pragma unroll
            for (int di = 0; di < 4; ++di) {
                s[di][0] = fmaf(a[di], b2.x, s[di][0]);
                s[di][1] = fmaf(a[di], b2.y, s[di][1]);
            }
        }
        #pragma unroll
        for (int di = 0; di < 4; ++di) {
            int i = iq * 4 + di;
            float mi = ms[i], li = ils[i];
            float2 p;
            p.x = __expf(s[di][0] - mi) * li;
            p.y = __expf(s[di][1] - mi) * li;
            *reinterpret_cast<float2*>(&Pt[i][jp * 2]) = p;
        }
        __syncthreads();

        // PV: acc[jj][q] += P[ii][j] * v[ii][c]; V float4 from global (L2)
        const float* vtt = vtb + (size_t)i0 * 128 + tc4 * 4;
        #pragma unroll 8
        for (int ii = 0; ii < 64; ++ii) {
            float2 p2 = *reinterpret_cast<const float2*>(&Pt[ii][tj2 * 2]);
            float4 v4 = *reinterpret_cast<const float4*>(vtt + (size_t)ii * 128);
            float vv[4] = {v4.x, v4.y, v4.z, v4.w};
            #pragma unroll
            for (int q = 0; q < 4; ++q) {
                acc[0][q] = fmaf(p2.x, vv[q], acc[0][q]);
                acc[1][q] = fmaf(p2.y, vv[q], acc[1][q]);
            }
        }
    }

    // epilogue: out = x + sc * attn; rows c0+cl0+tc4*4+q, cols j0+tj2*2
    const float sc = scale[0];
    const float* xb = x   + (size_t)n * NCH * HW;
    float*       ob = out + (size_t)n * NCH * HW;
    #pragma unroll
    for (int q = 0; q < 4; ++q) {
        size_t off = (size_t)(c0 + cl0 + tc4 * 4 + q) * HW + j0 + tj2 * 2;
        float2 xv = *reinterpret_cast<const float2*>(xb + off);
        float2 r;
        r.x = xv.x + sc * acc[0][q];
        r.y = xv.y + sc * acc[1][q];
        *reinterpret_cast<float2*>(ob + off) = r;
    }
}

extern "C" void kernel_launch(void* const* d_in, const int* in_sizes, int n_in,
                              void* d_out, int out_size, void* d_ws, size_t ws_size,
                              hipStream_t stream) {
    (void)in_sizes; (void)n_in; (void)out_size; (void)ws_size;
    const float* x  = (const float*)d_in[0];
    const float* w1 = (const float*)d_in[1];
    const float* w2 = (const float*)d_in[2];
    const float* wv = (const float*)d_in[3];
    const float* sc = (const float*)d_in[4];
    float* out = (float*)d_out;

    float* rr   = (float*)d_ws;                      // 1,048,576 fl
    float* mbuf = rr + (size_t)NB * 64 * HW;         // 16,384 fl
    float* lbuf = mbuf + (size_t)NB * HW;            // 16,384 fl
    float* vt   = lbuf + (size_t)NB * HW;            // 2,097,152 fl

    proj_rr_kernel<<<dim3(64, NB), 256, 0, stream>>>(x, w1, w2, rr);
    stats_kernel<<<dim3(64, NB), 512, 0, stream>>>(rr, mbuf, lbuf);
    for (int h = 0; h < 2; ++h) {
        proj_vt_kernel<<<dim3(64, 2, NB), 256, 0, stream>>>(x, wv, vt, h * 128);
        attn_kernel<<<dim3(64, 2, NB), 512, 0, stream>>>(rr, mbuf, lbuf, vt, x,
                                                         sc, out, h * 128);
    }
}

// Round 4
// 414.129 us; speedup vs baseline: 6.3661x; 3.1824x over previous
//
#include <hip/hip_runtime.h>
#include <math.h>

#define HW    4096      // 64*64
#define NCH   256       // C
#define NB    4         // batch

typedef __attribute__((ext_vector_type(8))) short short8b;  // 8 bf16 (4 VGPRs)
typedef __attribute__((ext_vector_type(4))) float f32x4;    // 4 fp32 acc

__device__ __forceinline__ unsigned short f2bf(float f) {
    unsigned int u = __float_as_uint(f);
    u += 0x7FFFu + ((u >> 16) & 1u);          // RNE; inputs finite
    return (unsigned short)(u >> 16);
}
__device__ __forceinline__ float bf2f(unsigned short h) {
    return __uint_as_float(((unsigned int)h) << 16);
}

// ws layout, total 12.13 MB:
//   rr   fp32 [n][64][4096]            (r1 rows 0-31, r2 rows 32-63)   4 MB
//   mbuf fp32 [n][4096]                                               64 KB
//   lbuf fp32 [n][4096]                                               64 KB
//   r1h/r1l/r2h/r2l bf16 [n][4096][32] (hi/lo splits, [i][o] layout) 4x1 MB
//   vtb  bf16 [n][128][128][32]        (V blocked: [i>>5][c][i&31])    4 MB/chunk

// ---------------------------------------------------------------------------
// rr[n][r][i] = sum_c W[r][c] * x[n][c][i]; also write hi/lo bf16 splits
// transposed to [i][o] for MFMA fragments.
// ---------------------------------------------------------------------------
__global__ __launch_bounds__(256) void proj_rr_kernel(
    const float* __restrict__ x, const float* __restrict__ w1,
    const float* __restrict__ w2, float* __restrict__ rr,
    unsigned short* __restrict__ r1h, unsigned short* __restrict__ r1l,
    unsigned short* __restrict__ r2h, unsigned short* __restrict__ r2l)
{
    __shared__ float aT[16][68];   // [k][m]
    __shared__ float bS[16][68];   // [k][i]

    const int t  = threadIdx.x;
    const int i0 = blockIdx.x * 64;
    const int n  = blockIdx.y;

    const int tm = t >> 4;
    const int ti = t & 15;

    const int ar = t >> 2;          // 0..63
    const int ak = (t & 3) * 4;
    const float* arow = (ar < 32) ? (w1 + (size_t)ar * NCH)
                                  : (w2 + (size_t)(ar - 32) * NCH);
    const float* xb = x + (size_t)n * NCH * HW;

    float acc[4][4] = {};

    for (int kc = 0; kc < NCH; kc += 16) {
        float4 av = *reinterpret_cast<const float4*>(arow + kc + ak);
        float4 bv = *reinterpret_cast<const float4*>(
            xb + (size_t)(kc + (t >> 4)) * HW + i0 + (t & 15) * 4);
        __syncthreads();
        aT[ak + 0][ar] = av.x;
        aT[ak + 1][ar] = av.y;
        aT[ak + 2][ar] = av.z;
        aT[ak + 3][ar] = av.w;
        *reinterpret_cast<float4*>(&bS[t >> 4][(t & 15) * 4]) = bv;
        __syncthreads();
        #pragma unroll
        for (int kk = 0; kk < 16; ++kk) {
            float4 a4 = *reinterpret_cast<const float4*>(&aT[kk][tm * 4]);
            float4 b4 = *reinterpret_cast<const float4*>(&bS[kk][ti * 4]);
            float a[4] = {a4.x, a4.y, a4.z, a4.w};
            float b[4] = {b4.x, b4.y, b4.z, b4.w};
            #pragma unroll
            for (int mm = 0; mm < 4; ++mm)
                #pragma unroll
                for (int jj = 0; jj < 4; ++jj)
                    acc[mm][jj] = fmaf(a[mm], b[jj], acc[mm][jj]);
        }
    }

    float* op = rr + (size_t)n * 64 * HW;
    #pragma unroll
    for (int mm = 0; mm < 4; ++mm) {
        float4 r;
        r.x = acc[mm][0]; r.y = acc[mm][1]; r.z = acc[mm][2]; r.w = acc[mm][3];
        *reinterpret_cast<float4*>(op + (size_t)(tm * 4 + mm) * HW + i0 + ti * 4) = r;
    }

    // hi/lo bf16 splits, layout [n][i][o]
    #pragma unroll
    for (int mm = 0; mm < 4; ++mm) {
        const int m = tm * 4 + mm;
        unsigned short* bh = (m < 32) ? r1h : r2h;
        unsigned short* bl = (m < 32) ? r1l : r2l;
        const int o = m & 31;
        #pragma unroll
        for (int jj = 0; jj < 4; ++jj) {
            const int i = i0 + ti * 4 + jj;
            float v = acc[mm][jj];
            unsigned short h = f2bf(v);
            unsigned short lo = f2bf(v - bf2f(h));
            size_t idx = ((size_t)n * HW + i) * 32 + o;
            bh[idx] = h;
            bl[idx] = lo;
        }
    }
}

// ---------------------------------------------------------------------------
// vtb blocked bf16: vtb[n][i>>5][c][i&31] = sum_k x[n][k][i]*wv[c0+c][k]
// ---------------------------------------------------------------------------
__global__ __launch_bounds__(256) void proj_vt_kernel(
    const float* __restrict__ x, const float* __restrict__ wv,
    unsigned short* __restrict__ vtb, int c0)
{
    __shared__ float xs[16][68];    // [k][i]
    __shared__ float wsT[16][68];   // [k][c]

    const int t  = threadIdx.x;
    const int i0 = blockIdx.x * 64;
    const int cB = blockIdx.y * 64;
    const int n  = blockIdx.z;

    const int im = t >> 4;    // i-quad
    const int jc = t & 15;    // c-quad

    const int cr = t >> 2;          // 0..63
    const int ck = (t & 3) * 4;
    const float* wrow = wv + (size_t)(c0 + cB + cr) * NCH;
    const float* xb = x + (size_t)n * NCH * HW;

    float acc[4][4] = {};

    for (int kc = 0; kc < NCH; kc += 16) {
        float4 xv = *reinterpret_cast<const float4*>(
            xb + (size_t)(kc + (t >> 4)) * HW + i0 + (t & 15) * 4);
        float4 wvv = *reinterpret_cast<const float4*>(wrow + kc + ck);
        __syncthreads();
        *reinterpret_cast<float4*>(&xs[t >> 4][(t & 15) * 4]) = xv;
        wsT[ck + 0][cr] = wvv.x;
        wsT[ck + 1][cr] = wvv.y;
        wsT[ck + 2][cr] = wvv.z;
        wsT[ck + 3][cr] = wvv.w;
        __syncthreads();
        #pragma unroll
        for (int kk = 0; kk < 16; ++kk) {
            float4 a4 = *reinterpret_cast<const float4*>(&xs[kk][im * 4]);
            float4 b4 = *reinterpret_cast<const float4*>(&wsT[kk][jc * 4]);
            float a[4] = {a4.x, a4.y, a4.z, a4.w};
            float b[4] = {b4.x, b4.y, b4.z, b4.w};
            #pragma unroll
            for (int ii = 0; ii < 4; ++ii)
                #pragma unroll
                for (int cc = 0; cc < 4; ++cc)
                    acc[ii][cc] = fmaf(a[ii], b[cc], acc[ii][cc]);
        }
    }

    unsigned short* op = vtb + (size_t)n * 524288;   // 128*128*32
    #pragma unroll
    for (int ii = 0; ii < 4; ++ii) {
        const int i = i0 + im * 4 + ii;
        #pragma unroll
        for (int cc = 0; cc < 4; ++cc) {
            const int c = cB + jc * 4 + cc;         // c-local in chunk [0,128)
            op[(size_t)(i >> 5) * 4096 + c * 32 + (i & 31)] = f2bf(acc[ii][cc]);
        }
    }
}

// ---------------------------------------------------------------------------
// Row softmax stats over j: m_i, l_i.  (fp32 VALU, unchanged)
// ---------------------------------------------------------------------------
__global__ __launch_bounds__(512) void stats_kernel(
    const float* __restrict__ rr, float* __restrict__ mbuf,
    float* __restrict__ lbuf)
{
    __shared__ float r1t[32][64];
    __shared__ float r2t[32][128];

    const int t  = threadIdx.x;
    const int i0 = blockIdx.x * 64;
    const int n  = blockIdx.y;

    const float* r1 = rr + (size_t)n * 64 * HW;
    const float* r2 = r1 + (size_t)32 * HW;

    {
        int o = t >> 4, c4 = (t & 15) * 4;
        *reinterpret_cast<float4*>(&r1t[o][c4]) =
            *reinterpret_cast<const float4*>(r1 + (size_t)o * HW + i0 + c4);
    }

    const int ti = t >> 5;   // 0..15
    const int tj = t & 31;   // 0..31
    float m[4], l[4];
    #pragma unroll
    for (int ii = 0; ii < 4; ++ii) { m[ii] = -INFINITY; l[ii] = 0.f; }

    for (int jb = 0; jb < 32; ++jb) {
        const int j0 = jb * 128;
        __syncthreads();
        {
            int o = t >> 4, c4 = (t & 15) * 4;
            *reinterpret_cast<float4*>(&r2t[o][c4]) =
                *reinterpret_cast<const float4*>(r2 + (size_t)o * HW + j0 + c4);
            *reinterpret_cast<float4*>(&r2t[o][c4 + 64]) =
                *reinterpret_cast<const float4*>(r2 + (size_t)o * HW + j0 + c4 + 64);
        }
        __syncthreads();

        float s[4][4] = {};
        #pragma unroll 8
        for (int o = 0; o < 32; ++o) {
            float4 a4 = *reinterpret_cast<const float4*>(&r1t[o][ti * 4]);
            float4 b4 = *reinterpret_cast<const float4*>(&r2t[o][tj * 4]);
            float a[4] = {a4.x, a4.y, a4.z, a4.w};
            float b[4] = {b4.x, b4.y, b4.z, b4.w};
            #pragma unroll
            for (int ii = 0; ii < 4; ++ii)
                #pragma unroll
                for (int jj = 0; jj < 4; ++jj)
                    s[ii][jj] = fmaf(a[ii], b[jj], s[ii][jj]);
        }

        #pragma unroll
        for (int ii = 0; ii < 4; ++ii) {
            float rm = fmaxf(fmaxf(s[ii][0], s[ii][1]), fmaxf(s[ii][2], s[ii][3]));
            for (int msk = 1; msk < 32; msk <<= 1)
                rm = fmaxf(rm, __shfl_xor(rm, msk, 64));
            float mn = fmaxf(m[ii], rm);
            float sum = __expf(s[ii][0] - mn) + __expf(s[ii][1] - mn)
                      + __expf(s[ii][2] - mn) + __expf(s[ii][3] - mn);
            for (int msk = 1; msk < 32; msk <<= 1)
                sum += __shfl_xor(sum, msk, 64);
            l[ii] = l[ii] * __expf(m[ii] - mn) + sum;
            m[ii] = mn;
        }
    }

    if (tj == 0) {
        #pragma unroll
        for (int ii = 0; ii < 4; ++ii) {
            mbuf[(size_t)n * HW + i0 + ti * 4 + ii] = m[ii];
            lbuf[(size_t)n * HW + i0 + ti * 4 + ii] = l[ii];
        }
    }
}

// ---------------------------------------------------------------------------
// MFMA attn: out[n][c0+c][j] = x + sc * sum_i V[c][i] * exp(S[i][j]-m_i)/l_i
// grid (128 j-blocks, 4 n), 256 thr (4 waves). Tile 32j x 128c; i-steps of 32.
// S via 3 split-bf16 MFMAs (K=32=OC); PV via bf16 MFMA, P through 2KB LDS.
// ---------------------------------------------------------------------------
__global__ __launch_bounds__(256) void attn_kernel(
    const unsigned short* __restrict__ r1h, const unsigned short* __restrict__ r1l,
    const unsigned short* __restrict__ r2h, const unsigned short* __restrict__ r2l,
    const float* __restrict__ mbuf, const float* __restrict__ lbuf,
    const unsigned short* __restrict__ vtb, const float* __restrict__ x,
    const float* __restrict__ scale, float* __restrict__ out, int c0)
{
    __shared__ float2 mil[HW];     // 32 KB: (m_i, 1/l_i)
    __shared__ uint4  pl[128];     // 2 KB: P tile, [j(32)][i(32)] bf16, swizzled

    const int t = threadIdx.x;
    const int w = t >> 6;          // wave 0..3
    const int l = t & 63;
    const int j0 = blockIdx.x * 32;
    const int n  = blockIdx.y;

    // preload (m, 1/l)
    for (int q = t; q < HW; q += 256)
        mil[q] = make_float2(mbuf[(size_t)n * HW + q],
                             1.0f / lbuf[(size_t)n * HW + q]);

    // persistent S B-fragments (r2 at this block's j), hi/lo
    const int jS = j0 + (w & 1) * 16 + (l & 15);
    const size_t rbase = ((size_t)n * HW + jS) * 32 + (l >> 4) * 8;
    const short8b bh = *reinterpret_cast<const short8b*>(r2h + rbase);
    const short8b blo = *reinterpret_cast<const short8b*>(r2l + rbase);

    const unsigned short* vtn = vtb + (size_t)n * 524288;
    const int iSrow = (w >> 1) * 16 + (l & 15);     // A-frag row (i) for S
    const int ilocb = (w >> 1) * 16 + (l >> 4) * 4; // D rows (i) for S out
    const int jloc  = (w & 1) * 16 + (l & 15);      // D col (j) for S out
    const int wr_off = jloc * 64 + (((ilocb * 2) ^ (((jloc >> 1) & 3) << 4)));
    const int i8b = (l >> 4) * 16;                  // B-frag k-chunk byte off

    f32x4 acc[2][2] = {};   // [ct][jt]

    __syncthreads();   // mil ready

    for (int it = 0; it < 128; ++it) {
        const int ib = it * 32;

        // ---- S phase: 3 split MFMAs ----
        const size_t ab = ((size_t)n * HW + ib + iSrow) * 32 + (l >> 4) * 8;
        short8b ah = *reinterpret_cast<const short8b*>(r1h + ab);
        short8b al = *reinterpret_cast<const short8b*>(r1l + ab);
        f32x4 s = {0.f, 0.f, 0.f, 0.f};
        s = __builtin_amdgcn_mfma_f32_16x16x32_bf16(al, bh,  s, 0, 0, 0);
        s = __builtin_amdgcn_mfma_f32_16x16x32_bf16(ah, blo, s, 0, 0, 0);
        s = __builtin_amdgcn_mfma_f32_16x16x32_bf16(ah, bh,  s, 0, 0, 0);

        // ---- P = exp(S - m) / l -> bf16 -> LDS ----
        float2 ml0 = mil[ib + ilocb + 0];
        float2 ml1 = mil[ib + ilocb + 1];
        float2 ml2 = mil[ib + ilocb + 2];
        float2 ml3 = mil[ib + ilocb + 3];
        unsigned int p01 = (unsigned int)f2bf(__expf(s[0] - ml0.x) * ml0.y)
                         | ((unsigned int)f2bf(__expf(s[1] - ml1.x) * ml1.y) << 16);
        unsigned int p23 = (unsigned int)f2bf(__expf(s[2] - ml2.x) * ml2.y)
                         | ((unsigned int)f2bf(__expf(s[3] - ml3.x) * ml3.y) << 16);
        *reinterpret_cast<uint2*>(reinterpret_cast<char*>(pl) + wr_off) =
            make_uint2(p01, p23);
        __syncthreads();

        // ---- PV phase ----
        short8b pb[2], va[2];
        #pragma unroll
        for (int jt = 0; jt < 2; ++jt) {
            int jl = jt * 16 + (l & 15);
            int off = jl * 64 + (i8b ^ (((jl >> 1) & 3) << 4));
            pb[jt] = *reinterpret_cast<const short8b*>(
                reinterpret_cast<const char*>(pl) + off);
        }
        #pragma unroll
        for (int ct = 0; ct < 2; ++ct) {
            int c = w * 32 + ct * 16 + (l & 15);
            va[ct] = *reinterpret_cast<const short8b*>(
                vtn + (size_t)it * 4096 + c * 32 + (l >> 4) * 8);
        }
        #pragma unroll
        for (int ct = 0; ct < 2; ++ct)
            #pragma unroll
            for (int jt = 0; jt < 2; ++jt)
                acc[ct][jt] = __builtin_amdgcn_mfma_f32_16x16x32_bf16(
                    va[ct], pb[jt], acc[ct][jt], 0, 0, 0);
        __syncthreads();   // PV done before next P overwrite
    }

    // ---- epilogue: out = x + sc * attn ----
    const float sc = scale[0];
    const float* xb = x   + (size_t)n * NCH * HW;
    float*       ob = out + (size_t)n * NCH * HW;
    #pragma unroll
    for (int ct = 0; ct < 2; ++ct) {
        #pragma unroll
        for (int jt = 0; jt < 2; ++jt) {
            const int cb = c0 + w * 32 + ct * 16 + (l >> 4) * 4;
            const int j  = j0 + jt * 16 + (l & 15);
            #pragma unroll
            for (int r = 0; r < 4; ++r) {
                size_t off = (size_t)(cb + r) * HW + j;
                ob[off] = xb[off] + sc * acc[ct][jt][r];
            }
        }
    }
}

extern "C" void kernel_launch(void* const* d_in, const int* in_sizes, int n_in,
                              void* d_out, int out_size, void* d_ws, size_t ws_size,
                              hipStream_t stream) {
    (void)in_sizes; (void)n_in; (void)out_size; (void)ws_size;
    const float* x  = (const float*)d_in[0];
    const float* w1 = (const float*)d_in[1];
    const float* w2 = (const float*)d_in[2];
    const float* wv = (const float*)d_in[3];
    const float* sc = (const float*)d_in[4];
    float* out = (float*)d_out;

    float* rr   = (float*)d_ws;                        // 1,048,576 fl
    float* mbuf = rr + (size_t)NB * 64 * HW;           // 16,384 fl
    float* lbuf = mbuf + (size_t)NB * HW;              // 16,384 fl
    unsigned short* r1h = (unsigned short*)(lbuf + (size_t)NB * HW);
    unsigned short* r1l = r1h + (size_t)NB * HW * 32;  // each 524,288 ush
    unsigned short* r2h = r1l + (size_t)NB * HW * 32;
    unsigned short* r2l = r2h + (size_t)NB * HW * 32;
    unsigned short* vtb = r2l + (size_t)NB * HW * 32;  // 2,097,152 ush (4 MB)

    proj_rr_kernel<<<dim3(64, NB), 256, 0, stream>>>(x, w1, w2, rr,
                                                     r1h, r1l, r2h, r2l);
    stats_kernel<<<dim3(64, NB), 512, 0, stream>>>(rr, mbuf, lbuf);
    for (int h = 0; h < 2; ++h) {
        proj_vt_kernel<<<dim3(64, 2, NB), 256, 0, stream>>>(x, wv, vtb, h * 128);
        attn_kernel<<<dim3(128, NB), 256, 0, stream>>>(
            r1h, r1l, r2h, r2l, mbuf, lbuf, vtb, x, sc, out, h * 128);
    }
}

// Round 5
// 334.503 us; speedup vs baseline: 7.8816x; 1.2380x over previous
//
#include <hip/hip_runtime.h>
#include <math.h>

#define HW    4096      // 64*64
#define NCH   256       // C
#define NB    4         // batch

typedef __attribute__((ext_vector_type(8))) short short8b;  // 8 bf16 (4 VGPRs)
typedef __attribute__((ext_vector_type(4))) float f32x4;    // 4 fp32 acc

__device__ __forceinline__ unsigned short f2bf(float f) {
    unsigned int u = __float_as_uint(f);
    u += 0x7FFFu + ((u >> 16) & 1u);          // RNE; inputs finite
    return (unsigned short)(u >> 16);
}
__device__ __forceinline__ float bf2f(unsigned short h) {
    return __uint_as_float(((unsigned int)h) << 16);
}

// ws layout, total 12.38 MB:
//   mpart fp32 [2][n][4096]            128 KB   (per-j-half softmax max)
//   lpart fp32 [2][n][4096]            128 KB   (per-j-half sumexp)
//   mbuf  fp32 [n][4096]                64 KB   (merged max)
//   ilbuf fp32 [n][4096]                64 KB   (merged 1/l)
//   r1h/r1l/r2h/r2l bf16 [n][4096][32] 4x1 MB   (hi/lo splits, [i][o])
//   vtb  bf16 [n][128][256][32]          8 MB   (V blocked: [i>>5][c][i&31])

// ---------------------------------------------------------------------------
// proj_rr: acc = sum_c W[r][c]*x[n][c][i], W=[w1;w2]; write hi/lo bf16 splits
// transposed to [i][o] for MFMA fragments.  grid (64, NB), 256 thr.
// ---------------------------------------------------------------------------
__global__ __launch_bounds__(256) void proj_rr_kernel(
    const float* __restrict__ x, const float* __restrict__ w1,
    const float* __restrict__ w2,
    unsigned short* __restrict__ r1h, unsigned short* __restrict__ r1l,
    unsigned short* __restrict__ r2h, unsigned short* __restrict__ r2l)
{
    __shared__ float aT[16][68];   // [k][m]
    __shared__ float bS[16][68];   // [k][i]

    const int t  = threadIdx.x;
    const int i0 = blockIdx.x * 64;
    const int n  = blockIdx.y;

    const int tm = t >> 4;
    const int ti = t & 15;

    const int ar = t >> 2;          // 0..63
    const int ak = (t & 3) * 4;
    const float* arow = (ar < 32) ? (w1 + (size_t)ar * NCH)
                                  : (w2 + (size_t)(ar - 32) * NCH);
    const float* xb = x + (size_t)n * NCH * HW;

    float acc[4][4] = {};

    for (int kc = 0; kc < NCH; kc += 16) {
        float4 av = *reinterpret_cast<const float4*>(arow + kc + ak);
        float4 bv = *reinterpret_cast<const float4*>(
            xb + (size_t)(kc + (t >> 4)) * HW + i0 + (t & 15) * 4);
        __syncthreads();
        aT[ak + 0][ar] = av.x;
        aT[ak + 1][ar] = av.y;
        aT[ak + 2][ar] = av.z;
        aT[ak + 3][ar] = av.w;
        *reinterpret_cast<float4*>(&bS[t >> 4][(t & 15) * 4]) = bv;
        __syncthreads();
        #pragma unroll
        for (int kk = 0; kk < 16; ++kk) {
            float4 a4 = *reinterpret_cast<const float4*>(&aT[kk][tm * 4]);
            float4 b4 = *reinterpret_cast<const float4*>(&bS[kk][ti * 4]);
            float a[4] = {a4.x, a4.y, a4.z, a4.w};
            float b[4] = {b4.x, b4.y, b4.z, b4.w};
            #pragma unroll
            for (int mm = 0; mm < 4; ++mm)
                #pragma unroll
                for (int jj = 0; jj < 4; ++jj)
                    acc[mm][jj] = fmaf(a[mm], b[jj], acc[mm][jj]);
        }
    }

    // hi/lo bf16 splits, layout [n][i][o]
    #pragma unroll
    for (int mm = 0; mm < 4; ++mm) {
        const int m = tm * 4 + mm;
        unsigned short* bh = (m < 32) ? r1h : r2h;
        unsigned short* bl = (m < 32) ? r1l : r2l;
        const int o = m & 31;
        #pragma unroll
        for (int jj = 0; jj < 4; ++jj) {
            const int i = i0 + ti * 4 + jj;
            float v = acc[mm][jj];
            unsigned short h = f2bf(v);
            unsigned short lo = f2bf(v - bf2f(h));
            size_t idx = ((size_t)n * HW + i) * 32 + o;
            bh[idx] = h;
            bl[idx] = lo;
        }
    }
}

// ---------------------------------------------------------------------------
// proj_vt: vtb[n][i>>5][c][i&31] = bf16( sum_k x[n][k][i]*wv[c][k] )
// grid (64 i-blk, 4 c-blk, NB), 256 thr.
// ---------------------------------------------------------------------------
__global__ __launch_bounds__(256) void proj_vt_kernel(
    const float* __restrict__ x, const float* __restrict__ wv,
    unsigned short* __restrict__ vtb)
{
    __shared__ float xs[16][68];    // [k][i]
    __shared__ float wsT[16][68];   // [k][c]

    const int t  = threadIdx.x;
    const int i0 = blockIdx.x * 64;
    const int cB = blockIdx.y * 64;
    const int n  = blockIdx.z;

    const int im = t >> 4;    // i-quad
    const int jc = t & 15;    // c-quad

    const int cr = t >> 2;          // 0..63
    const int ck = (t & 3) * 4;
    const float* wrow = wv + (size_t)(cB + cr) * NCH;
    const float* xb = x + (size_t)n * NCH * HW;

    float acc[4][4] = {};

    for (int kc = 0; kc < NCH; kc += 16) {
        float4 xv = *reinterpret_cast<const float4*>(
            xb + (size_t)(kc + (t >> 4)) * HW + i0 + (t & 15) * 4);
        float4 wvv = *reinterpret_cast<const float4*>(wrow + kc + ck);
        __syncthreads();
        *reinterpret_cast<float4*>(&xs[t >> 4][(t & 15) * 4]) = xv;
        wsT[ck + 0][cr] = wvv.x;
        wsT[ck + 1][cr] = wvv.y;
        wsT[ck + 2][cr] = wvv.z;
        wsT[ck + 3][cr] = wvv.w;
        __syncthreads();
        #pragma unroll
        for (int kk = 0; kk < 16; ++kk) {
            float4 a4 = *reinterpret_cast<const float4*>(&xs[kk][im * 4]);
            float4 b4 = *reinterpret_cast<const float4*>(&wsT[kk][jc * 4]);
            float a[4] = {a4.x, a4.y, a4.z, a4.w};
            float b[4] = {b4.x, b4.y, b4.z, b4.w};
            #pragma unroll
            for (int ii = 0; ii < 4; ++ii)
                #pragma unroll
                for (int cc = 0; cc < 4; ++cc)
                    acc[ii][cc] = fmaf(a[ii], b[cc], acc[ii][cc]);
        }
    }

    unsigned short* op = vtb + (size_t)n * HW * 256;
    #pragma unroll
    for (int ii = 0; ii < 4; ++ii) {
        const int i = i0 + im * 4 + ii;
        #pragma unroll
        for (int cc = 0; cc < 4; ++cc) {
            const int c = cB + jc * 4 + cc;
            op[(size_t)(i >> 5) * 8192 + c * 32 + (i & 31)] = f2bf(acc[ii][cc]);
        }
    }
}

// ---------------------------------------------------------------------------
// stats (split-bf16 MFMA, two-pass): per row i over j-half: max, sumexp.
// grid (64 i-blk, 2 j-half, NB), 256 thr (4 waves x 16 i each).
// Uses the IDENTICAL 3-MFMA sequence as attn -> m is an exact max.
// ---------------------------------------------------------------------------
__global__ __launch_bounds__(256) void stats_kernel(
    const unsigned short* __restrict__ r1h, const unsigned short* __restrict__ r1l,
    const unsigned short* __restrict__ r2h, const unsigned short* __restrict__ r2l,
    float* __restrict__ mpart, float* __restrict__ lpart)
{
    const int t = threadIdx.x;
    const int w = t >> 6, l = t & 63;
    const int lj = l & 15, lg = l >> 4;
    const int i0 = blockIdx.x * 64 + w * 16;
    const int jh = blockIdx.y * 2048;
    const int n  = blockIdx.z;
    const size_t nHW = (size_t)n * HW;

    const size_t ab = (nHW + i0 + lj) * 32 + lg * 8;
    const short8b ah = *reinterpret_cast<const short8b*>(r1h + ab);
    const short8b al = *reinterpret_cast<const short8b*>(r1l + ab);

    const size_t bbase = (nHW + jh + lj) * 32 + lg * 8;

    // pass 1: lane-local running max, cross-lane reduce once
    f32x4 mx = {-INFINITY, -INFINITY, -INFINITY, -INFINITY};
    {
        short8b bh = *reinterpret_cast<const short8b*>(r2h + bbase);
        short8b bl = *reinterpret_cast<const short8b*>(r2l + bbase);
        for (int jt = 0; jt < 128; ++jt) {
            short8b nh = bh, nl = bl;
            if (jt < 127) {
                nh = *reinterpret_cast<const short8b*>(r2h + bbase + (size_t)(jt + 1) * 512);
                nl = *reinterpret_cast<const short8b*>(r2l + bbase + (size_t)(jt + 1) * 512);
            }
            f32x4 s = {0.f, 0.f, 0.f, 0.f};
            s = __builtin_amdgcn_mfma_f32_16x16x32_bf16(al, bh, s, 0, 0, 0);
            s = __builtin_amdgcn_mfma_f32_16x16x32_bf16(ah, bl, s, 0, 0, 0);
            s = __builtin_amdgcn_mfma_f32_16x16x32_bf16(ah, bh, s, 0, 0, 0);
            #pragma unroll
            for (int r = 0; r < 4; ++r) mx[r] = fmaxf(mx[r], s[r]);
            bh = nh; bl = nl;
        }
    }
    #pragma unroll
    for (int msk = 1; msk < 16; msk <<= 1)
        #pragma unroll
        for (int r = 0; r < 4; ++r)
            mx[r] = fmaxf(mx[r], __shfl_xor(mx[r], msk, 64));

    // pass 2: sumexp
    f32x4 sm = {0.f, 0.f, 0.f, 0.f};
    {
        short8b bh = *reinterpret_cast<const short8b*>(r2h + bbase);
        short8b bl = *reinterpret_cast<const short8b*>(r2l + bbase);
        for (int jt = 0; jt < 128; ++jt) {
            short8b nh = bh, nl = bl;
            if (jt < 127) {
                nh = *reinterpret_cast<const short8b*>(r2h + bbase + (size_t)(jt + 1) * 512);
                nl = *reinterpret_cast<const short8b*>(r2l + bbase + (size_t)(jt + 1) * 512);
            }
            f32x4 s = {0.f, 0.f, 0.f, 0.f};
            s = __builtin_amdgcn_mfma_f32_16x16x32_bf16(al, bh, s, 0, 0, 0);
            s = __builtin_amdgcn_mfma_f32_16x16x32_bf16(ah, bl, s, 0, 0, 0);
            s = __builtin_amdgcn_mfma_f32_16x16x32_bf16(ah, bh, s, 0, 0, 0);
            #pragma unroll
            for (int r = 0; r < 4; ++r) sm[r] += __expf(s[r] - mx[r]);
            bh = nh; bl = nl;
        }
    }
    #pragma unroll
    for (int msk = 1; msk < 16; msk <<= 1)
        #pragma unroll
        for (int r = 0; r < 4; ++r)
            sm[r] += __shfl_xor(sm[r], msk, 64);

    if (lj == 0) {
        float* mp = mpart + ((size_t)blockIdx.y * NB + n) * HW + i0 + lg * 4;
        float* lp = lpart + ((size_t)blockIdx.y * NB + n) * HW + i0 + lg * 4;
        #pragma unroll
        for (int r = 0; r < 4; ++r) { mp[r] = mx[r]; lp[r] = sm[r]; }
    }
}

// ---------------------------------------------------------------------------
// merge the two j-halves: m = max, il = 1/(l1*e^{m1-m} + l2*e^{m2-m})
// ---------------------------------------------------------------------------
__global__ __launch_bounds__(256) void merge_kernel(
    const float* __restrict__ mpart, const float* __restrict__ lpart,
    float* __restrict__ mbuf, float* __restrict__ ilbuf)
{
    const int q = blockIdx.x * 256 + threadIdx.x;   // over NB*HW
    const int T = NB * HW;
    float m1 = mpart[q], m2 = mpart[T + q];
    float l1 = lpart[q], l2 = lpart[T + q];
    float m = fmaxf(m1, m2);
    float il = 1.0f / (l1 * __expf(m1 - m) + l2 * __expf(m2 - m));
    mbuf[q] = m; ilbuf[q] = il;
}

// ---------------------------------------------------------------------------
// attn: out[n][c][j] = x + sc * sum_i V[c][i] * exp(S[i][j]-m_i)/l_i
// grid (256 j-blocks, 2 c-halves, NB), 256 thr (4 waves).
// Tile 16 j x 128 c; i-steps of 64 (wave w computes S rows w*16..+16).
// P double-buffered in 4 KB LDS -> one barrier/iter; V + next A prefetched.
// ---------------------------------------------------------------------------
__global__ __launch_bounds__(256) void attn_kernel(
    const unsigned short* __restrict__ r1h, const unsigned short* __restrict__ r1l,
    const unsigned short* __restrict__ r2h, const unsigned short* __restrict__ r2l,
    const float* __restrict__ mbuf, const float* __restrict__ ilbuf,
    const unsigned short* __restrict__ vtb, const float* __restrict__ x,
    const float* __restrict__ scale, float* __restrict__ out)
{
    __shared__ char pl[2][2048];   // P dbuf: [j 16][i 64] bf16, XOR-swizzled

    const int t = threadIdx.x;
    const int w = t >> 6, l = t & 63;
    const int lj = l & 15, lg = l >> 4;
    const int j0 = blockIdx.x * 16;
    const int cbase = blockIdx.y * 128;
    const int n = blockIdx.z;
    const size_t nHW = (size_t)n * HW;

    // persistent S B-frags (r2 hi/lo at this block's j)
    const size_t rb = (nHW + j0 + lj) * 32 + lg * 8;
    const short8b bh = *reinterpret_cast<const short8b*>(r2h + rb);
    const short8b bl = *reinterpret_cast<const short8b*>(r2l + rb);

    const unsigned short* vtn = vtb + nHW * 256;
    const int swz = (lj & 7) << 4;
    const int wroff = lj * 128 + ((w * 32 + lg * 8) ^ swz);
    const int rd0 = lj * 128 + ((lg * 16) ^ swz);
    const int rd1 = lj * 128 + ((64 + lg * 16) ^ swz);
    const size_t vrow = (size_t)(cbase + w * 32 + lj) * 32 + lg * 8;

    // prologue: A-frags + (m, 1/l) for it = 0
    size_t abase = (nHW + w * 16 + lj) * 32 + lg * 8;
    short8b ah = *reinterpret_cast<const short8b*>(r1h + abase);
    short8b al = *reinterpret_cast<const short8b*>(r1l + abase);
    const float* mrow = mbuf + nHW + w * 16 + lg * 4;
    const float* irow = ilbuf + nHW + w * 16 + lg * 4;
    float4 m4 = *reinterpret_cast<const float4*>(mrow);
    float4 il4 = *reinterpret_cast<const float4*>(irow);

    f32x4 acc0 = {0.f, 0.f, 0.f, 0.f}, acc1 = {0.f, 0.f, 0.f, 0.f};

    for (int it = 0; it < 64; ++it) {
        // V loads for this step (consumed after the barrier)
        const unsigned short* vb = vtn + (size_t)(it * 2) * 8192 + vrow;
        short8b va00 = *reinterpret_cast<const short8b*>(vb);          // ct0 ks0
        short8b va01 = *reinterpret_cast<const short8b*>(vb + 8192);   // ct0 ks1
        short8b va10 = *reinterpret_cast<const short8b*>(vb + 512);    // ct1 ks0
        short8b va11 = *reinterpret_cast<const short8b*>(vb + 8704);   // ct1 ks1

        // S: 3 split MFMAs (identical sequence to stats)
        f32x4 s = {0.f, 0.f, 0.f, 0.f};
        s = __builtin_amdgcn_mfma_f32_16x16x32_bf16(al, bh, s, 0, 0, 0);
        s = __builtin_amdgcn_mfma_f32_16x16x32_bf16(ah, bl, s, 0, 0, 0);
        s = __builtin_amdgcn_mfma_f32_16x16x32_bf16(ah, bh, s, 0, 0, 0);

        // P = exp(S-m)/l -> bf16 -> LDS
        unsigned int p01 = (unsigned int)f2bf(__expf(s[0] - m4.x) * il4.x)
                         | ((unsigned int)f2bf(__expf(s[1] - m4.y) * il4.y) << 16);
        unsigned int p23 = (unsigned int)f2bf(__expf(s[2] - m4.z) * il4.z)
                         | ((unsigned int)f2bf(__expf(s[3] - m4.w) * il4.w) << 16);
        *reinterpret_cast<uint2*>(&pl[it & 1][wroff]) = make_uint2(p01, p23);

        // prefetch next A-frags + (m, 1/l)
        if (it < 63) {
            abase += 64 * 32;
            ah = *reinterpret_cast<const short8b*>(r1h + abase);
            al = *reinterpret_cast<const short8b*>(r1l + abase);
            m4 = *reinterpret_cast<const float4*>(mrow + (it + 1) * 64);
            il4 = *reinterpret_cast<const float4*>(irow + (it + 1) * 64);
        }
        __syncthreads();

        // PV: 4 MFMAs
        short8b pb0 = *reinterpret_cast<const short8b*>(&pl[it & 1][rd0]);
        short8b pb1 = *reinterpret_cast<const short8b*>(&pl[it & 1][rd1]);
        acc0 = __builtin_amdgcn_mfma_f32_16x16x32_bf16(va00, pb0, acc0, 0, 0, 0);
        acc0 = __builtin_amdgcn_mfma_f32_16x16x32_bf16(va01, pb1, acc0, 0, 0, 0);
        acc1 = __builtin_amdgcn_mfma_f32_16x16x32_bf16(va10, pb0, acc1, 0, 0, 0);
        acc1 = __builtin_amdgcn_mfma_f32_16x16x32_bf16(va11, pb1, acc1, 0, 0, 0);
    }

    // epilogue: out = x + sc * attn
    const float sc = scale[0];
    const float* xb = x   + nHW * NCH;
    float*       ob = out + nHW * NCH;
    #pragma unroll
    for (int ct = 0; ct < 2; ++ct) {
        f32x4 a = ct ? acc1 : acc0;
        const int cb = cbase + w * 32 + ct * 16 + lg * 4;
        #pragma unroll
        for (int r = 0; r < 4; ++r) {
            size_t off = (size_t)(cb + r) * HW + j0 + lj;
            ob[off] = xb[off] + sc * a[r];
        }
    }
}

extern "C" void kernel_launch(void* const* d_in, const int* in_sizes, int n_in,
                              void* d_out, int out_size, void* d_ws, size_t ws_size,
                              hipStream_t stream) {
    (void)in_sizes; (void)n_in; (void)out_size; (void)ws_size;
    const float* x  = (const float*)d_in[0];
    const float* w1 = (const float*)d_in[1];
    const float* w2 = (const float*)d_in[2];
    const float* wv = (const float*)d_in[3];
    const float* sc = (const float*)d_in[4];
    float* out = (float*)d_out;

    float* mpart = (float*)d_ws;                         // 32,768 fl
    float* lpart = mpart + (size_t)2 * NB * HW;          // 32,768 fl
    float* mbuf  = lpart + (size_t)2 * NB * HW;          // 16,384 fl
    float* ilbuf = mbuf  + (size_t)NB * HW;              // 16,384 fl
    unsigned short* r1h = (unsigned short*)(ilbuf + (size_t)NB * HW);
    unsigned short* r1l = r1h + (size_t)NB * HW * 32;    // each 524,288 ush
    unsigned short* r2h = r1l + (size_t)NB * HW * 32;
    unsigned short* r2l = r2h + (size_t)NB * HW * 32;
    unsigned short* vtb = r2l + (size_t)NB * HW * 32;    // 4,194,304 ush (8 MB)

    proj_rr_kernel<<<dim3(64, NB), 256, 0, stream>>>(x, w1, w2,
                                                     r1h, r1l, r2h, r2l);
    stats_kernel<<<dim3(64, 2, NB), 256, 0, stream>>>(r1h, r1l, r2h, r2l,
                                                      mpart, lpart);
    merge_kernel<<<dim3(NB * HW / 256), 256, 0, stream>>>(mpart, lpart,
                                                          mbuf, ilbuf);
    proj_vt_kernel<<<dim3(64, 4, NB), 256, 0, stream>>>(x, wv, vtb);
    attn_kernel<<<dim3(256, 2, NB), 256, 0, stream>>>(
        r1h, r1l, r2h, r2l, mbuf, ilbuf, vtb, x, sc, out);
}

// Round 6
// 265.996 us; speedup vs baseline: 9.9114x; 1.2575x over previous
//
#include <hip/hip_runtime.h>
#include <math.h>

#define HW    4096      // 64*64
#define NCH   256       // C
#define NB    4         // batch

typedef __attribute__((ext_vector_type(8))) short short8b;  // 8 bf16 (4 VGPRs)
typedef __attribute__((ext_vector_type(4))) float f32x4;    // 4 fp32 acc

__device__ __forceinline__ unsigned short f2bf(float f) {
    unsigned int u = __float_as_uint(f);
    u += 0x7FFFu + ((u >> 16) & 1u);          // RNE; inputs finite
    return (unsigned short)(u >> 16);
}
__device__ __forceinline__ float bf2f(unsigned short h) {
    return __uint_as_float(((unsigned int)h) << 16);
}

// ws layout, total 12.5 MB:
//   mpart fp32 [2][n][4096]            128 KB   (per-j-half approx max)
//   lpart fp32 [2][n][4096]            128 KB   (per-j-half sumexp)
//   mbuf  fp32 [n][4096]                64 KB   (merged m)
//   ilbuf fp32 [n][4096]                64 KB   (merged 1/l)
//   r1h/r1l/r2h/r2l bf16 [n][4096][32] 4x1 MB   (hi/lo splits, [i][o])
//   vtb  bf16 [n][128][256][32]          8 MB   (V blocked: [i>>5][c][i&31])
//   wvb  bf16 [256][256]               128 KB   (wv converted)

// ---------------------------------------------------------------------------
// proj_rr: acc = sum_c W[r][c]*x[n][c][i], W=[w1;w2]; write hi/lo bf16 splits
// transposed to [i][o] for MFMA fragments.  grid (64, NB), 256 thr.
// ---------------------------------------------------------------------------
__global__ __launch_bounds__(256) void proj_rr_kernel(
    const float* __restrict__ x, const float* __restrict__ w1,
    const float* __restrict__ w2,
    unsigned short* __restrict__ r1h, unsigned short* __restrict__ r1l,
    unsigned short* __restrict__ r2h, unsigned short* __restrict__ r2l)
{
    __shared__ float aT[16][68];   // [k][m]
    __shared__ float bS[16][68];   // [k][i]

    const int t  = threadIdx.x;
    const int i0 = blockIdx.x * 64;
    const int n  = blockIdx.y;

    const int tm = t >> 4;
    const int ti = t & 15;

    const int ar = t >> 2;          // 0..63
    const int ak = (t & 3) * 4;
    const float* arow = (ar < 32) ? (w1 + (size_t)ar * NCH)
                                  : (w2 + (size_t)(ar - 32) * NCH);
    const float* xb = x + (size_t)n * NCH * HW;

    float acc[4][4] = {};

    for (int kc = 0; kc < NCH; kc += 16) {
        float4 av = *reinterpret_cast<const float4*>(arow + kc + ak);
        float4 bv = *reinterpret_cast<const float4*>(
            xb + (size_t)(kc + (t >> 4)) * HW + i0 + (t & 15) * 4);
        __syncthreads();
        aT[ak + 0][ar] = av.x;
        aT[ak + 1][ar] = av.y;
        aT[ak + 2][ar] = av.z;
        aT[ak + 3][ar] = av.w;
        *reinterpret_cast<float4*>(&bS[t >> 4][(t & 15) * 4]) = bv;
        __syncthreads();
        #pragma unroll
        for (int kk = 0; kk < 16; ++kk) {
            float4 a4 = *reinterpret_cast<const float4*>(&aT[kk][tm * 4]);
            float4 b4 = *reinterpret_cast<const float4*>(&bS[kk][ti * 4]);
            float a[4] = {a4.x, a4.y, a4.z, a4.w};
            float b[4] = {b4.x, b4.y, b4.z, b4.w};
            #pragma unroll
            for (int mm = 0; mm < 4; ++mm)
                #pragma unroll
                for (int jj = 0; jj < 4; ++jj)
                    acc[mm][jj] = fmaf(a[mm], b[jj], acc[mm][jj]);
        }
    }

    // hi/lo bf16 splits, layout [n][i][o]
    #pragma unroll
    for (int mm = 0; mm < 4; ++mm) {
        const int m = tm * 4 + mm;
        unsigned short* bh = (m < 32) ? r1h : r2h;
        unsigned short* bl = (m < 32) ? r1l : r2l;
        const int o = m & 31;
        #pragma unroll
        for (int jj = 0; jj < 4; ++jj) {
            const int i = i0 + ti * 4 + jj;
            float v = acc[mm][jj];
            unsigned short h = f2bf(v);
            unsigned short lo = f2bf(v - bf2f(h));
            size_t idx = ((size_t)n * HW + i) * 32 + o;
            bh[idx] = h;
            bl[idx] = lo;
        }
    }
}

// ---------------------------------------------------------------------------
// wvb: wv fp32 -> bf16, layout unchanged [c][k].  grid (32), 256 thr.
// ---------------------------------------------------------------------------
__global__ __launch_bounds__(256) void wvb_kernel(
    const float* __restrict__ wv, unsigned short* __restrict__ wvb)
{
    const int q = (blockIdx.x * 256 + threadIdx.x) * 8;
    float4 a = *reinterpret_cast<const float4*>(wv + q);
    float4 b = *reinterpret_cast<const float4*>(wv + q + 4);
    short8b o;
    o[0] = (short)f2bf(a.x); o[1] = (short)f2bf(a.y);
    o[2] = (short)f2bf(a.z); o[3] = (short)f2bf(a.w);
    o[4] = (short)f2bf(b.x); o[5] = (short)f2bf(b.y);
    o[6] = (short)f2bf(b.z); o[7] = (short)f2bf(b.w);
    *reinterpret_cast<short8b*>(wvb + q) = o;
}

// ---------------------------------------------------------------------------
// proj_v (bf16 MFMA): vtb[n][i>>5][c][i&31] = sum_k wv[c][k] x[n][k][i]
// grid (64 i-blk, 4 c-blk, NB), 256 thr (4 waves: 2 i-sub x 2 c-sub of 32).
// x K-tiles staged+transposed+converted in LDS.
// ---------------------------------------------------------------------------
__global__ __launch_bounds__(256) void proj_v_kernel(
    const float* __restrict__ x, const unsigned short* __restrict__ wvb,
    unsigned short* __restrict__ vtb)
{
    __shared__ unsigned short xt[64][40];   // [i][k] bf16 (K-step 32, pad 40)

    const int t = threadIdx.x;
    const int w = t >> 6, l = t & 63;
    const int lj = l & 15, lg = l >> 4;
    const int iB = blockIdx.x * 64;
    const int cB = blockIdx.y * 64;
    const int n  = blockIdx.z;
    const float* xb = x + (size_t)n * NCH * HW;

    const int iw = (w >> 1) * 32;   // wave i-base within tile
    const int cw = (w & 1) * 32;    // wave c-base within tile

    f32x4 acc[2][2] = {};           // [isub][csub]

    const int kr = t >> 4;          // staging: k row 0..15
    const int ic = (t & 15) * 4;    // staging: i quad

    for (int kc = 0; kc < NCH; kc += 32) {
        float4 x0 = *reinterpret_cast<const float4*>(
            xb + (size_t)(kc + kr) * HW + iB + ic);
        float4 x1 = *reinterpret_cast<const float4*>(
            xb + (size_t)(kc + kr + 16) * HW + iB + ic);
        __syncthreads();
        xt[ic + 0][kr] = f2bf(x0.x); xt[ic + 1][kr] = f2bf(x0.y);
        xt[ic + 2][kr] = f2bf(x0.z); xt[ic + 3][kr] = f2bf(x0.w);
        xt[ic + 0][kr + 16] = f2bf(x1.x); xt[ic + 1][kr + 16] = f2bf(x1.y);
        xt[ic + 2][kr + 16] = f2bf(x1.z); xt[ic + 3][kr + 16] = f2bf(x1.w);
        __syncthreads();

        short8b xa[2], wb[2];
        #pragma unroll
        for (int is = 0; is < 2; ++is)
            xa[is] = *reinterpret_cast<const short8b*>(&xt[iw + is * 16 + lj][lg * 8]);
        #pragma unroll
        for (int cs = 0; cs < 2; ++cs)
            wb[cs] = *reinterpret_cast<const short8b*>(
                wvb + (size_t)(cB + cw + cs * 16 + lj) * NCH + kc + lg * 8);
        #pragma unroll
        for (int is = 0; is < 2; ++is)
            #pragma unroll
            for (int cs = 0; cs < 2; ++cs)
                acc[is][cs] = __builtin_amdgcn_mfma_f32_16x16x32_bf16(
                    xa[is], wb[cs], acc[is][cs], 0, 0, 0);
    }

    unsigned short* op = vtb + (size_t)n * HW * 256;
    #pragma unroll
    for (int is = 0; is < 2; ++is) {
        #pragma unroll
        for (int cs = 0; cs < 2; ++cs) {
            const int c = cB + cw + cs * 16 + lj;
            #pragma unroll
            for (int r = 0; r < 4; ++r) {
                const int i = iB + iw + is * 16 + lg * 4 + r;
                op[(size_t)(i >> 5) * 8192 + c * 32 + (i & 31)] =
                    f2bf(acc[is][cs][r]);
            }
        }
    }
}

// ---------------------------------------------------------------------------
// stats: per row i over j-half: approx max (pass 1, hi-only 1 MFMA) then
// exact-path sumexp (pass 2, 3 MFMAs matching attn).  grid (64, 2, NB).
// ---------------------------------------------------------------------------
__global__ __launch_bounds__(256) void stats_kernel(
    const unsigned short* __restrict__ r1h, const unsigned short* __restrict__ r1l,
    const unsigned short* __restrict__ r2h, const unsigned short* __restrict__ r2l,
    float* __restrict__ mpart, float* __restrict__ lpart)
{
    const int t = threadIdx.x;
    const int w = t >> 6, l = t & 63;
    const int lj = l & 15, lg = l >> 4;
    const int i0 = blockIdx.x * 64 + w * 16;
    const int jh = blockIdx.y * 2048;
    const int n  = blockIdx.z;
    const size_t nHW = (size_t)n * HW;

    const size_t ab = (nHW + i0 + lj) * 32 + lg * 8;
    const short8b ah = *reinterpret_cast<const short8b*>(r1h + ab);
    const short8b al = *reinterpret_cast<const short8b*>(r1l + ab);
    const size_t bbase = (nHW + jh + lj) * 32 + lg * 8;

    // pass 1: approx max via hi-only S (m need not be exact, only consistent)
    f32x4 mx = {-INFINITY, -INFINITY, -INFINITY, -INFINITY};
    {
        short8b bh = *reinterpret_cast<const short8b*>(r2h + bbase);
        for (int jt = 0; jt < 128; ++jt) {
            short8b nh = bh;
            if (jt < 127)
                nh = *reinterpret_cast<const short8b*>(r2h + bbase + (size_t)(jt + 1) * 512);
            f32x4 s = {0.f, 0.f, 0.f, 0.f};
            s = __builtin_amdgcn_mfma_f32_16x16x32_bf16(ah, bh, s, 0, 0, 0);
            #pragma unroll
            for (int r = 0; r < 4; ++r) mx[r] = fmaxf(mx[r], s[r]);
            bh = nh;
        }
    }
    #pragma unroll
    for (int msk = 1; msk < 16; msk <<= 1)
        #pragma unroll
        for (int r = 0; r < 4; ++r)
            mx[r] = fmaxf(mx[r], __shfl_xor(mx[r], msk, 64));

    // pass 2: exact-path sumexp (3-MFMA sequence identical to attn)
    f32x4 sm = {0.f, 0.f, 0.f, 0.f};
    {
        short8b bh = *reinterpret_cast<const short8b*>(r2h + bbase);
        short8b bl = *reinterpret_cast<const short8b*>(r2l + bbase);
        for (int jt = 0; jt < 128; ++jt) {
            short8b nh = bh, nl = bl;
            if (jt < 127) {
                nh = *reinterpret_cast<const short8b*>(r2h + bbase + (size_t)(jt + 1) * 512);
                nl = *reinterpret_cast<const short8b*>(r2l + bbase + (size_t)(jt + 1) * 512);
            }
            f32x4 s = {0.f, 0.f, 0.f, 0.f};
            s = __builtin_amdgcn_mfma_f32_16x16x32_bf16(al, bh, s, 0, 0, 0);
            s = __builtin_amdgcn_mfma_f32_16x16x32_bf16(ah, bl, s, 0, 0, 0);
            s = __builtin_amdgcn_mfma_f32_16x16x32_bf16(ah, bh, s, 0, 0, 0);
            #pragma unroll
            for (int r = 0; r < 4; ++r) sm[r] += __expf(s[r] - mx[r]);
            bh = nh; bl = nl;
        }
    }
    #pragma unroll
    for (int msk = 1; msk < 16; msk <<= 1)
        #pragma unroll
        for (int r = 0; r < 4; ++r)
            sm[r] += __shfl_xor(sm[r], msk, 64);

    if (lj == 0) {
        float* mp = mpart + ((size_t)blockIdx.y * NB + n) * HW + i0 + lg * 4;
        float* lp = lpart + ((size_t)blockIdx.y * NB + n) * HW + i0 + lg * 4;
        #pragma unroll
        for (int r = 0; r < 4; ++r) { mp[r] = mx[r]; lp[r] = sm[r]; }
    }
}

// ---------------------------------------------------------------------------
// merge the two j-halves: m = max, il = 1/(l1*e^{m1-m} + l2*e^{m2-m})
// ---------------------------------------------------------------------------
__global__ __launch_bounds__(256) void merge_kernel(
    const float* __restrict__ mpart, const float* __restrict__ lpart,
    float* __restrict__ mbuf, float* __restrict__ ilbuf)
{
    const int q = blockIdx.x * 256 + threadIdx.x;   // over NB*HW
    const int T = NB * HW;
    float m1 = mpart[q], m2 = mpart[T + q];
    float l1 = lpart[q], l2 = lpart[T + q];
    float m = fmaxf(m1, m2);
    float il = 1.0f / (l1 * __expf(m1 - m) + l2 * __expf(m2 - m));
    mbuf[q] = m; ilbuf[q] = il;
}

// ---------------------------------------------------------------------------
// attn: out[n][c][j] = x + sc * sum_i V[c][i] * exp(S[i][j]-m_i)/l_i
// grid (256 j-blocks, NB) = 1024 blocks, 256 thr (4 waves).
// Tile 16 j x 256 c (full C); i-steps of 64; wave w: S rows w*16..+16 and
// PV c-range w*64..+64.  P dbuf in 4 KB LDS; V/A/m prefetched.
// ---------------------------------------------------------------------------
__global__ __launch_bounds__(256) void attn_kernel(
    const unsigned short* __restrict__ r1h, const unsigned short* __restrict__ r1l,
    const unsigned short* __restrict__ r2h, const unsigned short* __restrict__ r2l,
    const float* __restrict__ mbuf, const float* __restrict__ ilbuf,
    const unsigned short* __restrict__ vtb, const float* __restrict__ x,
    const float* __restrict__ scale, float* __restrict__ out)
{
    __shared__ char pl[2][2048];   // P dbuf: [j 16][i 64] bf16, XOR-swizzled

    const int t = threadIdx.x;
    const int w = t >> 6, l = t & 63;
    const int lj = l & 15, lg = l >> 4;
    const int j0 = blockIdx.x * 16;
    const int n = blockIdx.y;
    const size_t nHW = (size_t)n * HW;

    // persistent S B-frags (r2 hi/lo at this block's j)
    const size_t rb = (nHW + j0 + lj) * 32 + lg * 8;
    const short8b bh = *reinterpret_cast<const short8b*>(r2h + rb);
    const short8b bl = *reinterpret_cast<const short8b*>(r2l + rb);

    const unsigned short* vtn = vtb + nHW * 256;
    const int swz = (lj & 7) << 4;
    const int wroff = lj * 128 + ((w * 32 + lg * 8) ^ swz);
    const int rd0 = lj * 128 + ((lg * 16) ^ swz);
    const int rd1 = lj * 128 + ((64 + lg * 16) ^ swz);
    const size_t vrow = (size_t)(w * 64 + lj) * 32 + lg * 8;

    // prologue: A-frags + (m, 1/l) for it = 0
    size_t abase = (nHW + w * 16 + lj) * 32 + lg * 8;
    short8b ah = *reinterpret_cast<const short8b*>(r1h + abase);
    short8b al = *reinterpret_cast<const short8b*>(r1l + abase);
    const float* mrow = mbuf + nHW + w * 16 + lg * 4;
    const float* irow = ilbuf + nHW + w * 16 + lg * 4;
    float4 m4 = *reinterpret_cast<const float4*>(mrow);
    float4 il4 = *reinterpret_cast<const float4*>(irow);

    f32x4 acc[4] = {};   // c-tiles ct*16 within wave's 64-c range

    for (int it = 0; it < 64; ++it) {
        // V loads for this step (consumed after the barrier; L3-resident)
        const unsigned short* vb = vtn + (size_t)(it * 2) * 8192 + vrow;
        short8b va[4][2];
        #pragma unroll
        for (int ct = 0; ct < 4; ++ct)
            #pragma unroll
            for (int ks = 0; ks < 2; ++ks)
                va[ct][ks] = *reinterpret_cast<const short8b*>(
                    vb + ct * 512 + ks * 8192);

        // S: 3 split MFMAs (identical sequence to stats pass 2)
        f32x4 s = {0.f, 0.f, 0.f, 0.f};
        s = __builtin_amdgcn_mfma_f32_16x16x32_bf16(al, bh, s, 0, 0, 0);
        s = __builtin_amdgcn_mfma_f32_16x16x32_bf16(ah, bl, s, 0, 0, 0);
        s = __builtin_amdgcn_mfma_f32_16x16x32_bf16(ah, bh, s, 0, 0, 0);

        // P = exp(S-m)/l -> bf16 -> LDS
        unsigned int p01 = (unsigned int)f2bf(__expf(s[0] - m4.x) * il4.x)
                         | ((unsigned int)f2bf(__expf(s[1] - m4.y) * il4.y) << 16);
        unsigned int p23 = (unsigned int)f2bf(__expf(s[2] - m4.z) * il4.z)
                         | ((unsigned int)f2bf(__expf(s[3] - m4.w) * il4.w) << 16);
        *reinterpret_cast<uint2*>(&pl[it & 1][wroff]) = make_uint2(p01, p23);

        // prefetch next A-frags + (m, 1/l)
        if (it < 63) {
            abase += 64 * 32;
            ah = *reinterpret_cast<const short8b*>(r1h + abase);
            al = *reinterpret_cast<const short8b*>(r1l + abase);
            m4 = *reinterpret_cast<const float4*>(mrow + (it + 1) * 64);
            il4 = *reinterpret_cast<const float4*>(irow + (it + 1) * 64);
        }
        __syncthreads();

        // PV: 8 MFMAs (4 c-tiles x 2 k-chunks)
        short8b pb0 = *reinterpret_cast<const short8b*>(&pl[it & 1][rd0]);
        short8b pb1 = *reinterpret_cast<const short8b*>(&pl[it & 1][rd1]);
        #pragma unroll
        for (int ct = 0; ct < 4; ++ct) {
            acc[ct] = __builtin_amdgcn_mfma_f32_16x16x32_bf16(
                va[ct][0], pb0, acc[ct], 0, 0, 0);
            acc[ct] = __builtin_amdgcn_mfma_f32_16x16x32_bf16(
                va[ct][1], pb1, acc[ct], 0, 0, 0);
        }
    }

    // epilogue: out = x + sc * attn
    const float sc = scale[0];
    const float* xb = x   + nHW * NCH;
    float*       ob = out + nHW * NCH;
    #pragma unroll
    for (int ct = 0; ct < 4; ++ct) {
        const int cb = w * 64 + ct * 16 + lg * 4;
        #pragma unroll
        for (int r = 0; r < 4; ++r) {
            size_t off = (size_t)(cb + r) * HW + j0 + lj;
            ob[off] = xb[off] + sc * acc[ct][r];
        }
    }
}

extern "C" void kernel_launch(void* const* d_in, const int* in_sizes, int n_in,
                              void* d_out, int out_size, void* d_ws, size_t ws_size,
                              hipStream_t stream) {
    (void)in_sizes; (void)n_in; (void)out_size; (void)ws_size;
    const float* x  = (const float*)d_in[0];
    const float* w1 = (const float*)d_in[1];
    const float* w2 = (const float*)d_in[2];
    const float* wv = (const float*)d_in[3];
    const float* sc = (const float*)d_in[4];
    float* out = (float*)d_out;

    float* mpart = (float*)d_ws;                         // 32,768 fl
    float* lpart = mpart + (size_t)2 * NB * HW;          // 32,768 fl
    float* mbuf  = lpart + (size_t)2 * NB * HW;          // 16,384 fl
    float* ilbuf = mbuf  + (size_t)NB * HW;              // 16,384 fl
    unsigned short* r1h = (unsigned short*)(ilbuf + (size_t)NB * HW);
    unsigned short* r1l = r1h + (size_t)NB * HW * 32;    // each 524,288 ush
    unsigned short* r2h = r1l + (size_t)NB * HW * 32;
    unsigned short* r2l = r2h + (size_t)NB * HW * 32;
    unsigned short* vtb = r2l + (size_t)NB * HW * 32;    // 4,194,304 ush (8 MB)
    unsigned short* wvb = vtb + (size_t)NB * HW * 256;   // 65,536 ush (128 KB)

    proj_rr_kernel<<<dim3(64, NB), 256, 0, stream>>>(x, w1, w2,
                                                     r1h, r1l, r2h, r2l);
    wvb_kernel<<<dim3(32), 256, 0, stream>>>(wv, wvb);
    stats_kernel<<<dim3(64, 2, NB), 256, 0, stream>>>(r1h, r1l, r2h, r2l,
                                                      mpart, lpart);
    merge_kernel<<<dim3(NB * HW / 256), 256, 0, stream>>>(mpart, lpart,
                                                          mbuf, ilbuf);
    proj_v_kernel<<<dim3(64, 4, NB), 256, 0, stream>>>(x, wvb, vtb);
    attn_kernel<<<dim3(256, NB), 256, 0, stream>>>(
        r1h, r1l, r2h, r2l, mbuf, ilbuf, vtb, x, sc, out);
}

// Round 7
// 241.188 us; speedup vs baseline: 10.9309x; 1.1029x over previous
//
#include <hip/hip_runtime.h>
#include <math.h>

#define HW    4096      // 64*64
#define NCH   256       // C
#define NB    4         // batch

typedef __attribute__((ext_vector_type(8))) short short8b;  // 8 bf16 (4 VGPRs)
typedef __attribute__((ext_vector_type(4))) float f32x4;    // 4 fp32 acc

__device__ __forceinline__ unsigned short f2bf(float f) {
    unsigned int u = __float_as_uint(f);
    u += 0x7FFFu + ((u >> 16) & 1u);          // RNE; inputs finite
    return (unsigned short)(u >> 16);
}
__device__ __forceinline__ float bf2f(unsigned short h) {
    return __uint_as_float(((unsigned int)h) << 16);
}

// ws layout, total 12.25 MB:
//   mbuf  fp32 [n][4096]                64 KB   (merged m)
//   ilbuf fp32 [n][4096]                64 KB   (merged 1/l)
//   r1h/r1l/r2h/r2l bf16 [n][4096][32] 4x1 MB   (hi/lo splits, [i][o])
//   vtb  bf16 [n][128][256][32]          8 MB   (V blocked: [i>>5][c][i&31])
//   wvb  bf16 [256][256]               128 KB   (wv converted)
//   mpart/lpart fp32 [4][n][4096]      512 KB   ALIAS vtb (consumed by merge
//                                               before proj_v writes vtb)

// ---------------------------------------------------------------------------
// proj_rr: acc = sum_c W[r][c]*x[n][c][i], W=[w1;w2]; write hi/lo bf16 splits
// transposed to [i][o].  grid (64 i-blk, 2 m-half, NB), 256 thr.
// ---------------------------------------------------------------------------
__global__ __launch_bounds__(256) void proj_rr_kernel(
    const float* __restrict__ x, const float* __restrict__ w1,
    const float* __restrict__ w2,
    unsigned short* __restrict__ r1h, unsigned short* __restrict__ r1l,
    unsigned short* __restrict__ r2h, unsigned short* __restrict__ r2l)
{
    __shared__ float aT[16][36];   // [k][m 32]
    __shared__ float bS[16][68];   // [k][i 64]

    const int t  = threadIdx.x;
    const int i0 = blockIdx.x * 64;
    const int mh = blockIdx.y * 32;
    const int n  = blockIdx.z;

    const int tm = t >> 4;         // 0..15 -> m = mh + tm*2 + mm
    const int ti = t & 15;         // 0..15 -> i = i0 + ti*4 + jj

    const int ar = t >> 3;         // A-load row 0..31
    const int ak = (t & 7) * 2;    // A-load k-pair
    const int gm = mh + ar;
    const float* arow = (gm < 32) ? (w1 + (size_t)gm * NCH)
                                  : (w2 + (size_t)(gm - 32) * NCH);
    const float* xb = x + (size_t)n * NCH * HW;

    float acc[2][4] = {};

    for (int kc = 0; kc < NCH; kc += 16) {
        float2 av = *reinterpret_cast<const float2*>(arow + kc + ak);
        float4 bv = *reinterpret_cast<const float4*>(
            xb + (size_t)(kc + (t >> 4)) * HW + i0 + (t & 15) * 4);
        __syncthreads();
        aT[ak + 0][ar] = av.x;
        aT[ak + 1][ar] = av.y;
        *reinterpret_cast<float4*>(&bS[t >> 4][(t & 15) * 4]) = bv;
        __syncthreads();
        #pragma unroll
        for (int kk = 0; kk < 16; ++kk) {
            float2 a2 = *reinterpret_cast<const float2*>(&aT[kk][tm * 2]);
            float4 b4 = *reinterpret_cast<const float4*>(&bS[kk][ti * 4]);
            float a[2] = {a2.x, a2.y};
            float b[4] = {b4.x, b4.y, b4.z, b4.w};
            #pragma unroll
            for (int mm = 0; mm < 2; ++mm)
                #pragma unroll
                for (int jj = 0; jj < 4; ++jj)
                    acc[mm][jj] = fmaf(a[mm], b[jj], acc[mm][jj]);
        }
    }

    // hi/lo bf16 splits, layout [n][i][o]
    #pragma unroll
    for (int mm = 0; mm < 2; ++mm) {
        const int m = mh + tm * 2 + mm;
        unsigned short* bhp = (m < 32) ? r1h : r2h;
        unsigned short* blp = (m < 32) ? r1l : r2l;
        const int o = m & 31;
        #pragma unroll
        for (int jj = 0; jj < 4; ++jj) {
            const int i = i0 + ti * 4 + jj;
            float v = acc[mm][jj];
            unsigned short h = f2bf(v);
            unsigned short lo = f2bf(v - bf2f(h));
            size_t idx = ((size_t)n * HW + i) * 32 + o;
            bhp[idx] = h;
            blp[idx] = lo;
        }
    }
}

// ---------------------------------------------------------------------------
// wvb: wv fp32 -> bf16, layout unchanged [c][k].  grid (32), 256 thr.
// ---------------------------------------------------------------------------
__global__ __launch_bounds__(256) void wvb_kernel(
    const float* __restrict__ wv, unsigned short* __restrict__ wvb)
{
    const int q = (blockIdx.x * 256 + threadIdx.x) * 8;
    float4 a = *reinterpret_cast<const float4*>(wv + q);
    float4 b = *reinterpret_cast<const float4*>(wv + q + 4);
    short8b o;
    o[0] = (short)f2bf(a.x); o[1] = (short)f2bf(a.y);
    o[2] = (short)f2bf(a.z); o[3] = (short)f2bf(a.w);
    o[4] = (short)f2bf(b.x); o[5] = (short)f2bf(b.y);
    o[6] = (short)f2bf(b.z); o[7] = (short)f2bf(b.w);
    *reinterpret_cast<short8b*>(wvb + q) = o;
}

// ---------------------------------------------------------------------------
// proj_v (bf16 MFMA): vtb[n][i>>5][c][i&31] = sum_k wv[c][k] x[n][k][i]
// grid (64 i-blk, 4 c-blk, NB), 256 thr.
// ---------------------------------------------------------------------------
__global__ __launch_bounds__(256) void proj_v_kernel(
    const float* __restrict__ x, const unsigned short* __restrict__ wvb,
    unsigned short* __restrict__ vtb)
{
    __shared__ unsigned short xt[64][40];   // [i][k] bf16 (K-step 32, pad 40)

    const int t = threadIdx.x;
    const int w = t >> 6, l = t & 63;
    const int lj = l & 15, lg = l >> 4;
    const int iB = blockIdx.x * 64;
    const int cB = blockIdx.y * 64;
    const int n  = blockIdx.z;
    const float* xb = x + (size_t)n * NCH * HW;

    const int iw = (w >> 1) * 32;   // wave i-base within tile
    const int cw = (w & 1) * 32;    // wave c-base within tile

    f32x4 acc[2][2] = {};           // [isub][csub]

    const int kr = t >> 4;          // staging: k row 0..15
    const int ic = (t & 15) * 4;    // staging: i quad

    for (int kc = 0; kc < NCH; kc += 32) {
        float4 x0 = *reinterpret_cast<const float4*>(
            xb + (size_t)(kc + kr) * HW + iB + ic);
        float4 x1 = *reinterpret_cast<const float4*>(
            xb + (size_t)(kc + kr + 16) * HW + iB + ic);
        __syncthreads();
        xt[ic + 0][kr] = f2bf(x0.x); xt[ic + 1][kr] = f2bf(x0.y);
        xt[ic + 2][kr] = f2bf(x0.z); xt[ic + 3][kr] = f2bf(x0.w);
        xt[ic + 0][kr + 16] = f2bf(x1.x); xt[ic + 1][kr + 16] = f2bf(x1.y);
        xt[ic + 2][kr + 16] = f2bf(x1.z); xt[ic + 3][kr + 16] = f2bf(x1.w);
        __syncthreads();

        short8b xa[2], wb[2];
        #pragma unroll
        for (int is = 0; is < 2; ++is)
            xa[is] = *reinterpret_cast<const short8b*>(&xt[iw + is * 16 + lj][lg * 8]);
        #pragma unroll
        for (int cs = 0; cs < 2; ++cs)
            wb[cs] = *reinterpret_cast<const short8b*>(
                wvb + (size_t)(cB + cw + cs * 16 + lj) * NCH + kc + lg * 8);
        #pragma unroll
        for (int is = 0; is < 2; ++is)
            #pragma unroll
            for (int cs = 0; cs < 2; ++cs)
                acc[is][cs] = __builtin_amdgcn_mfma_f32_16x16x32_bf16(
                    xa[is], wb[cs], acc[is][cs], 0, 0, 0);
    }

    unsigned short* op = vtb + (size_t)n * HW * 256;
    #pragma unroll
    for (int is = 0; is < 2; ++is) {
        #pragma unroll
        for (int cs = 0; cs < 2; ++cs) {
            const int c = cB + cw + cs * 16 + lj;
            #pragma unroll
            for (int r = 0; r < 4; ++r) {
                const int i = iB + iw + is * 16 + lg * 4 + r;
                op[(size_t)(i >> 5) * 8192 + c * 32 + (i & 31)] =
                    f2bf(acc[is][cs][r]);
            }
        }
    }
}

// ---------------------------------------------------------------------------
// stats: per row i over a j-quarter (1024 j): approx max (pass 1, hi-only)
// then exact-path sumexp (pass 2, 3 MFMAs matching attn).
// grid (64 i-blk, 4 j-quarter, NB) = 1024 blocks, 256 thr.
// ---------------------------------------------------------------------------
__global__ __launch_bounds__(256) void stats_kernel(
    const unsigned short* __restrict__ r1h, const unsigned short* __restrict__ r1l,
    const unsigned short* __restrict__ r2h, const unsigned short* __restrict__ r2l,
    float* __restrict__ mpart, float* __restrict__ lpart)
{
    const int t = threadIdx.x;
    const int w = t >> 6, l = t & 63;
    const int lj = l & 15, lg = l >> 4;
    const int i0 = blockIdx.x * 64 + w * 16;
    const int jh = blockIdx.y * 1024;
    const int n  = blockIdx.z;
    const size_t nHW = (size_t)n * HW;

    const size_t ab = (nHW + i0 + lj) * 32 + lg * 8;
    const short8b ah = *reinterpret_cast<const short8b*>(r1h + ab);
    const short8b al = *reinterpret_cast<const short8b*>(r1l + ab);
    const size_t bbase = (nHW + jh + lj) * 32 + lg * 8;

    // pass 1: approx max via hi-only S (m need not be exact, only consistent)
    f32x4 mx = {-INFINITY, -INFINITY, -INFINITY, -INFINITY};
    {
        short8b bh = *reinterpret_cast<const short8b*>(r2h + bbase);
        for (int jt = 0; jt < 64; ++jt) {
            short8b nh = bh;
            if (jt < 63)
                nh = *reinterpret_cast<const short8b*>(r2h + bbase + (size_t)(jt + 1) * 512);
            f32x4 s = {0.f, 0.f, 0.f, 0.f};
            s = __builtin_amdgcn_mfma_f32_16x16x32_bf16(ah, bh, s, 0, 0, 0);
            #pragma unroll
            for (int r = 0; r < 4; ++r) mx[r] = fmaxf(mx[r], s[r]);
            bh = nh;
        }
    }
    #pragma unroll
    for (int msk = 1; msk < 16; msk <<= 1)
        #pragma unroll
        for (int r = 0; r < 4; ++r)
            mx[r] = fmaxf(mx[r], __shfl_xor(mx[r], msk, 64));

    // pass 2: exact-path sumexp (3-MFMA sequence identical to attn)
    f32x4 sm = {0.f, 0.f, 0.f, 0.f};
    {
        short8b bh = *reinterpret_cast<const short8b*>(r2h + bbase);
        short8b bl = *reinterpret_cast<const short8b*>(r2l + bbase);
        for (int jt = 0; jt < 64; ++jt) {
            short8b nh = bh, nl = bl;
            if (jt < 63) {
                nh = *reinterpret_cast<const short8b*>(r2h + bbase + (size_t)(jt + 1) * 512);
                nl = *reinterpret_cast<const short8b*>(r2l + bbase + (size_t)(jt + 1) * 512);
            }
            f32x4 s = {0.f, 0.f, 0.f, 0.f};
            s = __builtin_amdgcn_mfma_f32_16x16x32_bf16(al, bh, s, 0, 0, 0);
            s = __builtin_amdgcn_mfma_f32_16x16x32_bf16(ah, bl, s, 0, 0, 0);
            s = __builtin_amdgcn_mfma_f32_16x16x32_bf16(ah, bh, s, 0, 0, 0);
            #pragma unroll
            for (int r = 0; r < 4; ++r) sm[r] += __expf(s[r] - mx[r]);
            bh = nh; bl = nl;
        }
    }
    #pragma unroll
    for (int msk = 1; msk < 16; msk <<= 1)
        #pragma unroll
        for (int r = 0; r < 4; ++r)
            sm[r] += __shfl_xor(sm[r], msk, 64);

    if (lj == 0) {
        float* mp = mpart + ((size_t)blockIdx.y * NB + n) * HW + i0 + lg * 4;
        float* lp = lpart + ((size_t)blockIdx.y * NB + n) * HW + i0 + lg * 4;
        #pragma unroll
        for (int r = 0; r < 4; ++r) { mp[r] = mx[r]; lp[r] = sm[r]; }
    }
}

// ---------------------------------------------------------------------------
// merge 4 j-quarters: m = max, il = 1/sum(l_p * e^{m_p - m})
// ---------------------------------------------------------------------------
__global__ __launch_bounds__(256) void merge_kernel(
    const float* __restrict__ mpart, const float* __restrict__ lpart,
    float* __restrict__ mbuf, float* __restrict__ ilbuf)
{
    const int q = blockIdx.x * 256 + threadIdx.x;   // over NB*HW
    const int T = NB * HW;
    float m0 = mpart[q], m1 = mpart[T + q];
    float m2 = mpart[2 * T + q], m3 = mpart[3 * T + q];
    float m = fmaxf(fmaxf(m0, m1), fmaxf(m2, m3));
    float il = 1.0f / (lpart[q]         * __expf(m0 - m)
                     + lpart[T + q]     * __expf(m1 - m)
                     + lpart[2 * T + q] * __expf(m2 - m)
                     + lpart[3 * T + q] * __expf(m3 - m));
    mbuf[q] = m; ilbuf[q] = il;
}

// ---------------------------------------------------------------------------
// attn (pipelined): out[n][c][j] = x + sc * sum_i V[c][i] * P[i][j]
// grid (256 j-blocks, NB) = 1024 blocks, 256 thr (4 waves).
// Tile 16 j x 256 c; i-steps of 64.  Software pipeline: iteration `it`
// computes S(it+1) -> pl[(it+1)&1] WHILE PV(it) consumes pl[it&1];
// one barrier per iter; S and PV MFMA streams are independent.
// ---------------------------------------------------------------------------
__global__ __launch_bounds__(256) void attn_kernel(
    const unsigned short* __restrict__ r1h, const unsigned short* __restrict__ r1l,
    const unsigned short* __restrict__ r2h, const unsigned short* __restrict__ r2l,
    const float* __restrict__ mbuf, const float* __restrict__ ilbuf,
    const unsigned short* __restrict__ vtb, const float* __restrict__ x,
    const float* __restrict__ scale, float* __restrict__ out)
{
    __shared__ char pl[2][2048];   // P dbuf: [j 16][i 64] bf16, XOR-swizzled

    const int t = threadIdx.x;
    const int w = t >> 6, l = t & 63;
    const int lj = l & 15, lg = l >> 4;
    const int j0 = blockIdx.x * 16;
    const int n = blockIdx.y;
    const size_t nHW = (size_t)n * HW;

    // persistent S B-frags (r2 hi/lo at this block's j)
    const size_t rb = (nHW + j0 + lj) * 32 + lg * 8;
    const short8b bh = *reinterpret_cast<const short8b*>(r2h + rb);
    const short8b bl = *reinterpret_cast<const short8b*>(r2l + rb);

    const unsigned short* vtn = vtb + nHW * 256;
    const int swz = (lj & 7) << 4;
    const int wroff = lj * 128 + ((w * 32 + lg * 8) ^ swz);
    const int rd0 = lj * 128 + ((lg * 16) ^ swz);
    const int rd1 = lj * 128 + ((64 + lg * 16) ^ swz);
    const size_t vrow = (size_t)(w * 64 + lj) * 32 + lg * 8;

    const float* mrow = mbuf + nHW + w * 16 + lg * 4;
    const float* irow = ilbuf + nHW + w * 16 + lg * 4;

    // ---- prologue: compute S(0), publish to pl[0]; preload A(1)/m(1) ----
    size_t abase = (nHW + w * 16 + lj) * 32 + lg * 8;
    short8b ah = *reinterpret_cast<const short8b*>(r1h + abase);
    short8b al = *reinterpret_cast<const short8b*>(r1l + abase);
    float4 m4 = *reinterpret_cast<const float4*>(mrow);
    float4 il4 = *reinterpret_cast<const float4*>(irow);
    {
        f32x4 s = {0.f, 0.f, 0.f, 0.f};
        s = __builtin_amdgcn_mfma_f32_16x16x32_bf16(al, bh, s, 0, 0, 0);
        s = __builtin_amdgcn_mfma_f32_16x16x32_bf16(ah, bl, s, 0, 0, 0);
        s = __builtin_amdgcn_mfma_f32_16x16x32_bf16(ah, bh, s, 0, 0, 0);
        unsigned int p01 = (unsigned int)f2bf(__expf(s[0] - m4.x) * il4.x)
                         | ((unsigned int)f2bf(__expf(s[1] - m4.y) * il4.y) << 16);
        unsigned int p23 = (unsigned int)f2bf(__expf(s[2] - m4.z) * il4.z)
                         | ((unsigned int)f2bf(__expf(s[3] - m4.w) * il4.w) << 16);
        *reinterpret_cast<uint2*>(&pl[0][wroff]) = make_uint2(p01, p23);
    }
    abase += 64 * 32;
    ah = *reinterpret_cast<const short8b*>(r1h + abase);
    al = *reinterpret_cast<const short8b*>(r1l + abase);
    m4 = *reinterpret_cast<const float4*>(mrow + 64);
    il4 = *reinterpret_cast<const float4*>(irow + 64);
    __syncthreads();   // pl[0] visible

    f32x4 acc[4] = {};   // c-tiles ct*16 within wave's 64-c range

    for (int it = 0; it < 64; ++it) {
        // V(it) loads (global, L2/L3-resident) — issued first, consumed last
        const unsigned short* vb = vtn + (size_t)(it * 2) * 8192 + vrow;
        short8b va[4][2];
        #pragma unroll
        for (int ct = 0; ct < 4; ++ct)
            #pragma unroll
            for (int ks = 0; ks < 2; ++ks)
                va[ct][ks] = *reinterpret_cast<const short8b*>(
                    vb + ct * 512 + ks * 8192);

        // S(it+1): independent of PV(it) — fills the pipe
        if (it < 63) {
            f32x4 s = {0.f, 0.f, 0.f, 0.f};
            s = __builtin_amdgcn_mfma_f32_16x16x32_bf16(al, bh, s, 0, 0, 0);
            s = __builtin_amdgcn_mfma_f32_16x16x32_bf16(ah, bl, s, 0, 0, 0);
            s = __builtin_amdgcn_mfma_f32_16x16x32_bf16(ah, bh, s, 0, 0, 0);
            unsigned int p01 = (unsigned int)f2bf(__expf(s[0] - m4.x) * il4.x)
                             | ((unsigned int)f2bf(__expf(s[1] - m4.y) * il4.y) << 16);
            unsigned int p23 = (unsigned int)f2bf(__expf(s[2] - m4.z) * il4.z)
                             | ((unsigned int)f2bf(__expf(s[3] - m4.w) * il4.w) << 16);
            *reinterpret_cast<uint2*>(&pl[(it + 1) & 1][wroff]) =
                make_uint2(p01, p23);
            if (it < 62) {   // prefetch A(it+2), m(it+2)
                abase += 64 * 32;
                ah = *reinterpret_cast<const short8b*>(r1h + abase);
                al = *reinterpret_cast<const short8b*>(r1l + abase);
                m4 = *reinterpret_cast<const float4*>(mrow + (it + 2) * 64);
                il4 = *reinterpret_cast<const float4*>(irow + (it + 2) * 64);
            }
        }

        // PV(it): read P(it) from pl[it&1], 8 MFMAs
        short8b pb0 = *reinterpret_cast<const short8b*>(&pl[it & 1][rd0]);
        short8b pb1 = *reinterpret_cast<const short8b*>(&pl[it & 1][rd1]);
        #pragma unroll
        for (int ct = 0; ct < 4; ++ct) {
            acc[ct] = __builtin_amdgcn_mfma_f32_16x16x32_bf16(
                va[ct][0], pb0, acc[ct], 0, 0, 0);
            acc[ct] = __builtin_amdgcn_mfma_f32_16x16x32_bf16(
                va[ct][1], pb1, acc[ct], 0, 0, 0);
        }
        __syncthreads();   // P(it+1) published; pl[it&1] reads complete
    }

    // epilogue: out = x + sc * attn
    const float sc = scale[0];
    const float* xb = x   + nHW * NCH;
    float*       ob = out + nHW * NCH;
    #pragma unroll
    for (int ct = 0; ct < 4; ++ct) {
        const int cb = w * 64 + ct * 16 + lg * 4;
        #pragma unroll
        for (int r = 0; r < 4; ++r) {
            size_t off = (size_t)(cb + r) * HW + j0 + lj;
            ob[off] = xb[off] + sc * acc[ct][r];
        }
    }
}

extern "C" void kernel_launch(void* const* d_in, const int* in_sizes, int n_in,
                              void* d_out, int out_size, void* d_ws, size_t ws_size,
                              hipStream_t stream) {
    (void)in_sizes; (void)n_in; (void)out_size; (void)ws_size;
    const float* x  = (const float*)d_in[0];
    const float* w1 = (const float*)d_in[1];
    const float* w2 = (const float*)d_in[2];
    const float* wv = (const float*)d_in[3];
    const float* sc = (const float*)d_in[4];
    float* out = (float*)d_out;

    float* mbuf  = (float*)d_ws;                         // 16,384 fl
    float* ilbuf = mbuf + (size_t)NB * HW;               // 16,384 fl
    unsigned short* r1h = (unsigned short*)(ilbuf + (size_t)NB * HW);
    unsigned short* r1l = r1h + (size_t)NB * HW * 32;    // each 524,288 ush
    unsigned short* r2h = r1l + (size_t)NB * HW * 32;
    unsigned short* r2l = r2h + (size_t)NB * HW * 32;
    unsigned short* vtb = r2l + (size_t)NB * HW * 32;    // 4,194,304 ush (8 MB)
    unsigned short* wvb = vtb + (size_t)NB * HW * 256;   // 65,536 ush (128 KB)
    // mpart/lpart alias vtb: fully consumed by merge before proj_v writes vtb
    float* mpart = (float*)vtb;                          // 4*NB*HW fl (256 KB)
    float* lpart = mpart + (size_t)4 * NB * HW;          // 4*NB*HW fl (256 KB)

    proj_rr_kernel<<<dim3(64, 2, NB), 256, 0, stream>>>(x, w1, w2,
                                                        r1h, r1l, r2h, r2l);
    stats_kernel<<<dim3(64, 4, NB), 256, 0, stream>>>(r1h, r1l, r2h, r2l,
                                                      mpart, lpart);
    merge_kernel<<<dim3(NB * HW / 256), 256, 0, stream>>>(mpart, lpart,
                                                          mbuf, ilbuf);
    wvb_kernel<<<dim3(32), 256, 0, stream>>>(wv, wvb);
    proj_v_kernel<<<dim3(64, 4, NB), 256, 0, stream>>>(x, wvb, vtb);
    attn_kernel<<<dim3(256, NB), 256, 0, stream>>>(
        r1h, r1l, r2h, r2l, mbuf, ilbuf, vtb, x, sc, out);
}

// Round 8
// 181.198 us; speedup vs baseline: 14.5498x; 1.3311x over previous
//
#include <hip/hip_runtime.h>
#include <math.h>

#define HW    4096      // 64*64
#define NCH   256       // C
#define NB    4         // batch
#define L2E   1.44269504088896340736f

typedef __attribute__((ext_vector_type(8))) short short8b;  // 8 bf16 (4 VGPRs)
typedef __attribute__((ext_vector_type(4))) float f32x4;    // 4 fp32 acc

__device__ __forceinline__ unsigned short f2bf(float f) {
    unsigned int u = __float_as_uint(f);
    u += 0x7FFFu + ((u >> 16) & 1u);          // RNE; inputs finite
    return (unsigned short)(u >> 16);
}
__device__ __forceinline__ float bf2f(unsigned short h) {
    return __uint_as_float(((unsigned int)h) << 16);
}
// pack 2 fp32 -> 2 bf16 in one instr (T12 primitive); lo = a, hi = b
__device__ __forceinline__ unsigned int cvtpk_bf16(float a, float b) {
    unsigned int r;
    asm("v_cvt_pk_bf16_f32 %0, %1, %2" : "=v"(r) : "v"(a), "v"(b));
    return r;
}

// ws layout, total 12.25 MB:
//   ebuf  fp32 [n][4096]                64 KB   (-m*log2e - log2(l))
//   spare fp32 [n][4096]                64 KB   (unused)
//   r1h/r1l/r2h/r2l bf16 [n][4096][32] 4x1 MB   (hi/lo splits, [i][o])
//   vtb  bf16 [n][128][256][32]          8 MB   (V blocked: [i>>5][c][i&31])
//   wvb  bf16 [256][256]               128 KB   (wv converted)
//   mpart/lpart fp32 [4][n][4096]      512 KB   ALIAS vtb (consumed by merge
//                                               before proj_v writes vtb)

// ---------------------------------------------------------------------------
// proj_rr: acc = sum_c W[r][c]*x[n][c][i], W=[w1;w2]; write hi/lo bf16 splits
// transposed to [i][o].  grid (64 i-blk, 2 m-half, NB), 256 thr.
// ---------------------------------------------------------------------------
__global__ __launch_bounds__(256) void proj_rr_kernel(
    const float* __restrict__ x, const float* __restrict__ w1,
    const float* __restrict__ w2,
    unsigned short* __restrict__ r1h, unsigned short* __restrict__ r1l,
    unsigned short* __restrict__ r2h, unsigned short* __restrict__ r2l)
{
    __shared__ float aT[16][36];   // [k][m 32]
    __shared__ float bS[16][68];   // [k][i 64]

    const int t  = threadIdx.x;
    const int i0 = blockIdx.x * 64;
    const int mh = blockIdx.y * 32;
    const int n  = blockIdx.z;

    const int tm = t >> 4;         // 0..15 -> m = mh + tm*2 + mm
    const int ti = t & 15;         // 0..15 -> i = i0 + ti*4 + jj

    const int ar = t >> 3;         // A-load row 0..31
    const int ak = (t & 7) * 2;    // A-load k-pair
    const int gm = mh + ar;
    const float* arow = (gm < 32) ? (w1 + (size_t)gm * NCH)
                                  : (w2 + (size_t)(gm - 32) * NCH);
    const float* xb = x + (size_t)n * NCH * HW;

    float acc[2][4] = {};

    for (int kc = 0; kc < NCH; kc += 16) {
        float2 av = *reinterpret_cast<const float2*>(arow + kc + ak);
        float4 bv = *reinterpret_cast<const float4*>(
            xb + (size_t)(kc + (t >> 4)) * HW + i0 + (t & 15) * 4);
        __syncthreads();
        aT[ak + 0][ar] = av.x;
        aT[ak + 1][ar] = av.y;
        *reinterpret_cast<float4*>(&bS[t >> 4][(t & 15) * 4]) = bv;
        __syncthreads();
        #pragma unroll
        for (int kk = 0; kk < 16; ++kk) {
            float2 a2 = *reinterpret_cast<const float2*>(&aT[kk][tm * 2]);
            float4 b4 = *reinterpret_cast<const float4*>(&bS[kk][ti * 4]);
            float a[2] = {a2.x, a2.y};
            float b[4] = {b4.x, b4.y, b4.z, b4.w};
            #pragma unroll
            for (int mm = 0; mm < 2; ++mm)
                #pragma unroll
                for (int jj = 0; jj < 4; ++jj)
                    acc[mm][jj] = fmaf(a[mm], b[jj], acc[mm][jj]);
        }
    }

    // hi/lo bf16 splits, layout [n][i][o]
    #pragma unroll
    for (int mm = 0; mm < 2; ++mm) {
        const int m = mh + tm * 2 + mm;
        unsigned short* bhp = (m < 32) ? r1h : r2h;
        unsigned short* blp = (m < 32) ? r1l : r2l;
        const int o = m & 31;
        #pragma unroll
        for (int jj = 0; jj < 4; ++jj) {
            const int i = i0 + ti * 4 + jj;
            float v = acc[mm][jj];
            unsigned short h = f2bf(v);
            unsigned short lo = f2bf(v - bf2f(h));
            size_t idx = ((size_t)n * HW + i) * 32 + o;
            bhp[idx] = h;
            blp[idx] = lo;
        }
    }
}

// ---------------------------------------------------------------------------
// wvb: wv fp32 -> bf16, layout unchanged [c][k].  grid (32), 256 thr.
// ---------------------------------------------------------------------------
__global__ __launch_bounds__(256) void wvb_kernel(
    const float* __restrict__ wv, unsigned short* __restrict__ wvb)
{
    const int q = (blockIdx.x * 256 + threadIdx.x) * 8;
    float4 a = *reinterpret_cast<const float4*>(wv + q);
    float4 b = *reinterpret_cast<const float4*>(wv + q + 4);
    short8b o;
    o[0] = (short)f2bf(a.x); o[1] = (short)f2bf(a.y);
    o[2] = (short)f2bf(a.z); o[3] = (short)f2bf(a.w);
    o[4] = (short)f2bf(b.x); o[5] = (short)f2bf(b.y);
    o[6] = (short)f2bf(b.z); o[7] = (short)f2bf(b.w);
    *reinterpret_cast<short8b*>(wvb + q) = o;
}

// ---------------------------------------------------------------------------
// proj_v (bf16 MFMA): vtb[n][i>>5][c][i&31] = sum_k wv[c][k] x[n][k][i]
// grid (64 i-blk, 4 c-blk, NB), 256 thr.
// ---------------------------------------------------------------------------
__global__ __launch_bounds__(256) void proj_v_kernel(
    const float* __restrict__ x, const unsigned short* __restrict__ wvb,
    unsigned short* __restrict__ vtb)
{
    __shared__ unsigned short xt[64][40];   // [i][k] bf16 (K-step 32, pad 40)

    const int t = threadIdx.x;
    const int w = t >> 6, l = t & 63;
    const int lj = l & 15, lg = l >> 4;
    const int iB = blockIdx.x * 64;
    const int cB = blockIdx.y * 64;
    const int n  = blockIdx.z;
    const float* xb = x + (size_t)n * NCH * HW;

    const int iw = (w >> 1) * 32;   // wave i-base within tile
    const int cw = (w & 1) * 32;    // wave c-base within tile

    f32x4 acc[2][2] = {};           // [isub][csub]

    const int kr = t >> 4;          // staging: k row 0..15
    const int ic = (t & 15) * 4;    // staging: i quad

    for (int kc = 0; kc < NCH; kc += 32) {
        float4 x0 = *reinterpret_cast<const float4*>(
            xb + (size_t)(kc + kr) * HW + iB + ic);
        float4 x1 = *reinterpret_cast<const float4*>(
            xb + (size_t)(kc + kr + 16) * HW + iB + ic);
        __syncthreads();
        xt[ic + 0][kr] = f2bf(x0.x); xt[ic + 1][kr] = f2bf(x0.y);
        xt[ic + 2][kr] = f2bf(x0.z); xt[ic + 3][kr] = f2bf(x0.w);
        xt[ic + 0][kr + 16] = f2bf(x1.x); xt[ic + 1][kr + 16] = f2bf(x1.y);
        xt[ic + 2][kr + 16] = f2bf(x1.z); xt[ic + 3][kr + 16] = f2bf(x1.w);
        __syncthreads();

        short8b xa[2], wb[2];
        #pragma unroll
        for (int is = 0; is < 2; ++is)
            xa[is] = *reinterpret_cast<const short8b*>(&xt[iw + is * 16 + lj][lg * 8]);
        #pragma unroll
        for (int cs = 0; cs < 2; ++cs)
            wb[cs] = *reinterpret_cast<const short8b*>(
                wvb + (size_t)(cB + cw + cs * 16 + lj) * NCH + kc + lg * 8);
        #pragma unroll
        for (int is = 0; is < 2; ++is)
            #pragma unroll
            for (int cs = 0; cs < 2; ++cs)
                acc[is][cs] = __builtin_amdgcn_mfma_f32_16x16x32_bf16(
                    xa[is], wb[cs], acc[is][cs], 0, 0, 0);
    }

    unsigned short* op = vtb + (size_t)n * HW * 256;
    #pragma unroll
    for (int is = 0; is < 2; ++is) {
        #pragma unroll
        for (int cs = 0; cs < 2; ++cs) {
            const int c = cB + cw + cs * 16 + lj;
            #pragma unroll
            for (int r = 0; r < 4; ++r) {
                const int i = iB + iw + is * 16 + lg * 4 + r;
                op[(size_t)(i >> 5) * 8192 + c * 32 + (i & 31)] =
                    f2bf(acc[is][cs][r]);
            }
        }
    }
}

// ---------------------------------------------------------------------------
// stats: per row i over a j-quarter (1024 j): approx max (pass 1, hi-only)
// then exact-path sumexp (pass 2, 3 MFMAs matching attn).
// grid (64 i-blk, 4 j-quarter, NB) = 1024 blocks, 256 thr.
// ---------------------------------------------------------------------------
__global__ __launch_bounds__(256) void stats_kernel(
    const unsigned short* __restrict__ r1h, const unsigned short* __restrict__ r1l,
    const unsigned short* __restrict__ r2h, const unsigned short* __restrict__ r2l,
    float* __restrict__ mpart, float* __restrict__ lpart)
{
    const int t = threadIdx.x;
    const int w = t >> 6, l = t & 63;
    const int lj = l & 15, lg = l >> 4;
    const int i0 = blockIdx.x * 64 + w * 16;
    const int jh = blockIdx.y * 1024;
    const int n  = blockIdx.z;
    const size_t nHW = (size_t)n * HW;

    const size_t ab = (nHW + i0 + lj) * 32 + lg * 8;
    const short8b ah = *reinterpret_cast<const short8b*>(r1h + ab);
    const short8b al = *reinterpret_cast<const short8b*>(r1l + ab);
    const size_t bbase = (nHW + jh + lj) * 32 + lg * 8;

    // pass 1: approx max via hi-only S (m need not be exact, only consistent)
    f32x4 mx = {-INFINITY, -INFINITY, -INFINITY, -INFINITY};
    {
        short8b bh = *reinterpret_cast<const short8b*>(r2h + bbase);
        for (int jt = 0; jt < 64; ++jt) {
            short8b nh = bh;
            if (jt < 63)
                nh = *reinterpret_cast<const short8b*>(r2h + bbase + (size_t)(jt + 1) * 512);
            f32x4 s = {0.f, 0.f, 0.f, 0.f};
            s = __builtin_amdgcn_mfma_f32_16x16x32_bf16(ah, bh, s, 0, 0, 0);
            #pragma unroll
            for (int r = 0; r < 4; ++r) mx[r] = fmaxf(mx[r], s[r]);
            bh = nh;
        }
    }
    #pragma unroll
    for (int msk = 1; msk < 16; msk <<= 1)
        #pragma unroll
        for (int r = 0; r < 4; ++r)
            mx[r] = fmaxf(mx[r], __shfl_xor(mx[r], msk, 64));

    // pass 2: exact-path sumexp (3-MFMA sequence identical to attn)
    f32x4 sm = {0.f, 0.f, 0.f, 0.f};
    {
        short8b bh = *reinterpret_cast<const short8b*>(r2h + bbase);
        short8b bl = *reinterpret_cast<const short8b*>(r2l + bbase);
        for (int jt = 0; jt < 64; ++jt) {
            short8b nh = bh, nl = bl;
            if (jt < 63) {
                nh = *reinterpret_cast<const short8b*>(r2h + bbase + (size_t)(jt + 1) * 512);
                nl = *reinterpret_cast<const short8b*>(r2l + bbase + (size_t)(jt + 1) * 512);
            }
            f32x4 s = {0.f, 0.f, 0.f, 0.f};
            s = __builtin_amdgcn_mfma_f32_16x16x32_bf16(al, bh, s, 0, 0, 0);
            s = __builtin_amdgcn_mfma_f32_16x16x32_bf16(ah, bl, s, 0, 0, 0);
            s = __builtin_amdgcn_mfma_f32_16x16x32_bf16(ah, bh, s, 0, 0, 0);
            #pragma unroll
            for (int r = 0; r < 4; ++r) sm[r] += __expf(s[r] - mx[r]);
            bh = nh; bl = nl;
        }
    }
    #pragma unroll
    for (int msk = 1; msk < 16; msk <<= 1)
        #pragma unroll
        for (int r = 0; r < 4; ++r)
            sm[r] += __shfl_xor(sm[r], msk, 64);

    if (lj == 0) {
        float* mp = mpart + ((size_t)blockIdx.y * NB + n) * HW + i0 + lg * 4;
        float* lp = lpart + ((size_t)blockIdx.y * NB + n) * HW + i0 + lg * 4;
        #pragma unroll
        for (int r = 0; r < 4; ++r) { mp[r] = mx[r]; lp[r] = sm[r]; }
    }
}

// ---------------------------------------------------------------------------
// merge 4 j-quarters -> ebuf = -m*log2e - log2(l)  (so P = exp2(s*log2e + e))
// ---------------------------------------------------------------------------
__global__ __launch_bounds__(256) void merge_kernel(
    const float* __restrict__ mpart, const float* __restrict__ lpart,
    float* __restrict__ ebuf)
{
    const int q = blockIdx.x * 256 + threadIdx.x;   // over NB*HW
    const int T = NB * HW;
    float m0 = mpart[q], m1 = mpart[T + q];
    float m2 = mpart[2 * T + q], m3 = mpart[3 * T + q];
    float m = fmaxf(fmaxf(m0, m1), fmaxf(m2, m3));
    float lsum = lpart[q]         * __expf(m0 - m)
               + lpart[T + q]     * __expf(m1 - m)
               + lpart[2 * T + q] * __expf(m2 - m)
               + lpart[3 * T + q] * __expf(m3 - m);
    ebuf[q] = -m * L2E - log2f(lsum);
}

// ---------------------------------------------------------------------------
// attn: out[n][c][j] = x + sc * sum_i V[c][i] * exp2(S[i][j]*log2e + e_i)
// grid 512 linear blocks, 512 thr (8 waves).  XCD-aware: xcd = bid&7 hosts
// n = xcd>>1 (vtb[n] 2MB + r1[n] 1MB stay L2-resident per XCD).
// Tile 32 j x 256 c; i-steps of 64.  Wave (iw=w&3, jw=w>>2): S frag
// (16i x 16j); PV: wave covers c w*32..+32, both j-halves.
// P dbuf 8 KB LDS; pipeline S(it+1) over PV(it); one barrier/iter.
// ---------------------------------------------------------------------------
__global__ __launch_bounds__(512) void attn_kernel(
    const unsigned short* __restrict__ r1h, const unsigned short* __restrict__ r1l,
    const unsigned short* __restrict__ r2h, const unsigned short* __restrict__ r2l,
    const float* __restrict__ ebuf, const unsigned short* __restrict__ vtb,
    const float* __restrict__ x, const float* __restrict__ scale,
    float* __restrict__ out)
{
    __shared__ char pl[2][4096];   // P dbuf: [32 j][64 i] bf16, XOR-swizzled

    const int t = threadIdx.x;
    const int w = t >> 6, l = t & 63;
    const int lj = l & 15, lg = l >> 4;

    const int bid = blockIdx.x;
    const int xcd = bid & 7;
    const int n   = xcd >> 1;
    const int j0  = ((xcd & 1) * 64 + (bid >> 3)) * 32;
    const size_t nHW = (size_t)n * HW;

    const int iw = w & 3;        // S i-slice (16 rows)
    const int jw = w >> 2;       // S j-half (16 cols)

    // persistent S B-frags (r2 hi/lo at this wave's j)
    const size_t rb = (nHW + j0 + jw * 16 + lj) * 32 + lg * 8;
    const short8b bh = *reinterpret_cast<const short8b*>(r2h + rb);
    const short8b bl = *reinterpret_cast<const short8b*>(r2l + rb);

    const unsigned short* vtn = vtb + nHW * 256;
    const int swz = (lj & 7) << 4;
    const int wroff = (jw * 16 + lj) * 128 + ((iw * 32 + lg * 8) ^ swz);
    int rdo[2][2];
    #pragma unroll
    for (int jf = 0; jf < 2; ++jf)
        #pragma unroll
        for (int ks = 0; ks < 2; ++ks)
            rdo[jf][ks] = (jf * 16 + lj) * 128 + ((ks * 64 + lg * 16) ^ swz);
    const size_t vrow = (size_t)(w * 32 + lj) * 32 + lg * 8;

    const float* erow = ebuf + nHW + iw * 16 + lg * 4;

    // ---- prologue: S(0) -> pl[0]; preload A(1)/e(1) ----
    size_t abase = (nHW + iw * 16 + lj) * 32 + lg * 8;
    short8b ah = *reinterpret_cast<const short8b*>(r1h + abase);
    short8b al = *reinterpret_cast<const short8b*>(r1l + abase);
    float4 e4 = *reinterpret_cast<const float4*>(erow);
    {
        f32x4 s = {0.f, 0.f, 0.f, 0.f};
        s = __builtin_amdgcn_mfma_f32_16x16x32_bf16(al, bh, s, 0, 0, 0);
        s = __builtin_amdgcn_mfma_f32_16x16x32_bf16(ah, bl, s, 0, 0, 0);
        s = __builtin_amdgcn_mfma_f32_16x16x32_bf16(ah, bh, s, 0, 0, 0);
        float p0 = __builtin_amdgcn_exp2f(fmaf(s[0], L2E, e4.x));
        float p1 = __builtin_amdgcn_exp2f(fmaf(s[1], L2E, e4.y));
        float p2 = __builtin_amdgcn_exp2f(fmaf(s[2], L2E, e4.z));
        float p3 = __builtin_amdgcn_exp2f(fmaf(s[3], L2E, e4.w));
        *reinterpret_cast<uint2*>(&pl[0][wroff]) =
            make_uint2(cvtpk_bf16(p0, p1), cvtpk_bf16(p2, p3));
    }
    abase += 64 * 32;
    ah = *reinterpret_cast<const short8b*>(r1h + abase);
    al = *reinterpret_cast<const short8b*>(r1l + abase);
    e4 = *reinterpret_cast<const float4*>(erow + 64);
    __syncthreads();   // pl[0] visible

    f32x4 acc[2][2] = {};   // [cfrag][jfrag]

    for (int it = 0; it < 64; ++it) {
        // V(it) loads (L2-resident) — issued first, consumed last
        const unsigned short* vb = vtn + (size_t)(it * 2) * 8192 + vrow;
        short8b va[2][2];
        #pragma unroll
        for (int cf = 0; cf < 2; ++cf)
            #pragma unroll
            for (int ks = 0; ks < 2; ++ks)
                va[cf][ks] = *reinterpret_cast<const short8b*>(
                    vb + cf * 512 + ks * 8192);

        // S(it+1): independent of PV(it)
        if (it < 63) {
            f32x4 s = {0.f, 0.f, 0.f, 0.f};
            s = __builtin_amdgcn_mfma_f32_16x16x32_bf16(al, bh, s, 0, 0, 0);
            s = __builtin_amdgcn_mfma_f32_16x16x32_bf16(ah, bl, s, 0, 0, 0);
            s = __builtin_amdgcn_mfma_f32_16x16x32_bf16(ah, bh, s, 0, 0, 0);
            float p0 = __builtin_amdgcn_exp2f(fmaf(s[0], L2E, e4.x));
            float p1 = __builtin_amdgcn_exp2f(fmaf(s[1], L2E, e4.y));
            float p2 = __builtin_amdgcn_exp2f(fmaf(s[2], L2E, e4.z));
            float p3 = __builtin_amdgcn_exp2f(fmaf(s[3], L2E, e4.w));
            *reinterpret_cast<uint2*>(&pl[(it + 1) & 1][wroff]) =
                make_uint2(cvtpk_bf16(p0, p1), cvtpk_bf16(p2, p3));
            if (it < 62) {   // prefetch A(it+2), e(it+2)
                abase += 64 * 32;
                ah = *reinterpret_cast<const short8b*>(r1h + abase);
                al = *reinterpret_cast<const short8b*>(r1l + abase);
                e4 = *reinterpret_cast<const float4*>(erow + (it + 2) * 64);
            }
        }

        // PV(it): 8 MFMAs (2 c-frags x 2 j-frags x 2 k-chunks)
        short8b pb[2][2];
        #pragma unroll
        for (int jf = 0; jf < 2; ++jf)
            #pragma unroll
            for (int ks = 0; ks < 2; ++ks)
                pb[jf][ks] = *reinterpret_cast<const short8b*>(
                    &pl[it & 1][rdo[jf][ks]]);
        #pragma unroll
        for (int cf = 0; cf < 2; ++cf)
            #pragma unroll
            for (int jf = 0; jf < 2; ++jf) {
                acc[cf][jf] = __builtin_amdgcn_mfma_f32_16x16x32_bf16(
                    va[cf][0], pb[jf][0], acc[cf][jf], 0, 0, 0);
                acc[cf][jf] = __builtin_amdgcn_mfma_f32_16x16x32_bf16(
                    va[cf][1], pb[jf][1], acc[cf][jf], 0, 0, 0);
            }
        __syncthreads();   // P(it+1) published; pl[it&1] reads complete
    }

    // epilogue: out = x + sc * attn
    const float sc = scale[0];
    const float* xb = x   + nHW * NCH;
    float*       ob = out + nHW * NCH;
    #pragma unroll
    for (int cf = 0; cf < 2; ++cf) {
        #pragma unroll
        for (int jf = 0; jf < 2; ++jf) {
            const int cb = w * 32 + cf * 16 + lg * 4;
            const int j  = j0 + jf * 16 + lj;
            #pragma unroll
            for (int r = 0; r < 4; ++r) {
                size_t off = (size_t)(cb + r) * HW + j;
                ob[off] = xb[off] + sc * acc[cf][jf][r];
            }
        }
    }
}

extern "C" void kernel_launch(void* const* d_in, const int* in_sizes, int n_in,
                              void* d_out, int out_size, void* d_ws, size_t ws_size,
                              hipStream_t stream) {
    (void)in_sizes; (void)n_in; (void)out_size; (void)ws_size;
    const float* x  = (const float*)d_in[0];
    const float* w1 = (const float*)d_in[1];
    const float* w2 = (const float*)d_in[2];
    const float* wv = (const float*)d_in[3];
    const float* sc = (const float*)d_in[4];
    float* out = (float*)d_out;

    float* ebuf  = (float*)d_ws;                         // 16,384 fl
    float* spare = ebuf + (size_t)NB * HW;               // 16,384 fl (unused)
    unsigned short* r1h = (unsigned short*)(spare + (size_t)NB * HW);
    unsigned short* r1l = r1h + (size_t)NB * HW * 32;    // each 524,288 ush
    unsigned short* r2h = r1l + (size_t)NB * HW * 32;
    unsigned short* r2l = r2h + (size_t)NB * HW * 32;
    unsigned short* vtb = r2l + (size_t)NB * HW * 32;    // 4,194,304 ush (8 MB)
    unsigned short* wvb = vtb + (size_t)NB * HW * 256;   // 65,536 ush (128 KB)
    // mpart/lpart alias vtb: fully consumed by merge before proj_v writes vtb
    float* mpart = (float*)vtb;                          // 4*NB*HW fl (256 KB)
    float* lpart = mpart + (size_t)4 * NB * HW;          // 4*NB*HW fl (256 KB)

    proj_rr_kernel<<<dim3(64, 2, NB), 256, 0, stream>>>(x, w1, w2,
                                                        r1h, r1l, r2h, r2l);
    stats_kernel<<<dim3(64, 4, NB), 256, 0, stream>>>(r1h, r1l, r2h, r2l,
                                                      mpart, lpart);
    merge_kernel<<<dim3(NB * HW / 256), 256, 0, stream>>>(mpart, lpart, ebuf);
    wvb_kernel<<<dim3(32), 256, 0, stream>>>(wv, wvb);
    proj_v_kernel<<<dim3(64, 4, NB), 256, 0, stream>>>(x, wvb, vtb);
    attn_kernel<<<dim3(512), 512, 0, stream>>>(
        r1h, r1l, r2h, r2l, ebuf, vtb, x, sc, out);
}